// Round 1
// baseline (1178.368 us; speedup 1.0000x reference)
//
#include <hip/hip_runtime.h>
#include <cstdint>

// ---------------- problem constants ----------------
constexpr int B_ = 8, N_ = 2048, D_ = 128, NW = 64;   // NW = words per bitset row
constexpr int EMAX = 131072, E32 = EMAX / 32;          // per-batch edge capacity
constexpr int RPS = 2064;                              // rowptr stride per batch
constexpr int TDIL = 10;

// ---------------- workspace layout (bytes) ----------------
// region0: bitset (4MB) during preprocessing, reused as agg (8MB) later
constexpr size_t OFF_BITSET = 0;
constexpr size_t OFF_AGG    = 0;
constexpr size_t OFF_H1     = (size_t)8  << 20;
constexpr size_t OFF_H2     = (size_t)16 << 20;
constexpr size_t OFF_H3     = (size_t)24 << 20;
constexpr size_t OFF_COLS   = (size_t)32 << 20;   // u16 [B][EMAX]  (2MB)
constexpr size_t OFF_MATE   = (size_t)34 << 20;   // u32 [B][EMAX]  (4MB)
constexpr size_t OFF_RP     = (size_t)38 << 20;   // u32 [B][RPS]
constexpr size_t OFF_DEG0   = OFF_RP   + ((size_t)128 << 10);
constexpr size_t OFF_DEGF   = OFF_DEG0 + ((size_t)64  << 10);
constexpr size_t OFF_ALIVE  = OFF_DEGF + ((size_t)64  << 10);  // u32 [B][E32]
constexpr size_t OFF_BN     = OFF_ALIVE + ((size_t)128 << 10); // 3*256 floats

// ---------------- K0: zero BN stats ----------------
__global__ void k0_zero(float* bn) {
    for (int i = threadIdx.x; i < 768; i += 256) bn[i] = 0.f;
}

// ---------------- K1: adj (fp32 0/1) -> bitset + degrees ----------------
__global__ __launch_bounds__(256) void k1_bitset(const float* __restrict__ adj,
        uint32_t* __restrict__ bitset, uint32_t* __restrict__ deg0) {
    int row  = blockIdx.x * 4 + (threadIdx.x >> 6);
    int lane = threadIdx.x & 63;
    const float* ar = adj + (size_t)row * N_;
    uint32_t myw = 0;
    #pragma unroll 4
    for (int it = 0; it < 32; ++it) {
        float v = ar[it * 64 + lane];
        unsigned long long m = __ballot(v != 0.0f);
        if (lane == 2 * it)          myw = (uint32_t)m;
        else if (lane == 2 * it + 1) myw = (uint32_t)(m >> 32);
    }
    bitset[(size_t)row * NW + lane] = myw;
    int pc = __popc(myw);
    #pragma unroll
    for (int off = 32; off >= 1; off >>= 1) pc += __shfl_xor(pc, off);
    if (lane == 0) deg0[row] = (uint32_t)pc;
}

// ---------------- K2: per-batch prefix sum of degrees -> rowptr ----------------
__global__ __launch_bounds__(256) void k2_rowptr(const uint32_t* __restrict__ deg0,
        uint32_t* __restrict__ rowptr) {
    int b = blockIdx.x, t = threadIdx.x;
    __shared__ uint32_t tsum[256];
    uint32_t v[8]; uint32_t s = 0;
    #pragma unroll
    for (int j = 0; j < 8; ++j) { v[j] = deg0[b * N_ + t * 8 + j]; s += v[j]; v[j] = s; }
    tsum[t] = s;
    __syncthreads();
    for (int off = 1; off < 256; off <<= 1) {
        uint32_t xv = (t >= off) ? tsum[t - off] : 0u;
        __syncthreads();
        tsum[t] += xv;
        __syncthreads();
    }
    uint32_t excl = tsum[t] - s;
    uint32_t* rp = rowptr + (size_t)b * RPS;
    if (t == 0) rp[0] = 0;
    #pragma unroll
    for (int j = 0; j < 8; ++j) {
        uint32_t val = excl + v[j];
        if (val > (uint32_t)EMAX) val = EMAX;   // safety clamp
        rp[t * 8 + j + 1] = val;
    }
}

// ---------------- K3: fill sorted column lists ----------------
__global__ __launch_bounds__(256) void k3_cols(const uint32_t* __restrict__ bitset,
        const uint32_t* __restrict__ rowptr, uint16_t* __restrict__ cols) {
    int row  = blockIdx.x * 4 + (threadIdx.x >> 6);
    int lane = threadIdx.x & 63;
    int b = row >> 11, n = row & (N_ - 1);
    uint32_t w = bitset[(size_t)row * NW + lane];
    uint32_t pc = __popc(w);
    uint32_t inc = pc;
    #pragma unroll
    for (int off = 1; off < 64; off <<= 1) {
        uint32_t t = __shfl_up(inc, off);
        if (lane >= off) inc += t;
    }
    uint32_t base = rowptr[(size_t)b * RPS + n] + (inc - pc);
    uint16_t* cb = cols + (size_t)b * EMAX;
    while (w) {
        int bit = __builtin_ctz(w); w &= w - 1;
        if (base < (uint32_t)EMAX) cb[base] = (uint16_t)(lane * 32 + bit);
        ++base;
    }
}

// ---------------- K4: mate pointers via binary search (symmetric adj) ----------------
__global__ __launch_bounds__(256) void k4_mate(const uint16_t* __restrict__ cols,
        const uint32_t* __restrict__ rowptr, uint32_t* __restrict__ mate) {
    int row  = blockIdx.x * 4 + (threadIdx.x >> 6);
    int lane = threadIdx.x & 63;
    int b = row >> 11, n = row & (N_ - 1);
    const uint32_t* rpb = rowptr + (size_t)b * RPS;
    const uint16_t* cb  = cols + (size_t)b * EMAX;
    uint32_t start = rpb[n], end = rpb[n + 1];
    for (uint32_t e = start + lane; e < end; e += 64) {
        int j = cb[e];
        uint32_t lo = rpb[j], hi = rpb[j + 1];
        while (lo < hi) {
            uint32_t mid = (lo + hi) >> 1;
            if ((int)cb[mid] < n) lo = mid + 1; else hi = mid;
        }
        mate[(size_t)b * EMAX + e] = lo;
    }
}

// ---------------- K5: sequential dilation (1 wave per batch) ----------------
// Faithful to the reference scan: per row n (in order), on the CURRENT adjacency:
//   num<=T_DIL -> remove all neighbors; else remove ranks ceil(num/2) and num (if even).
// Removal clears edge + mate (symmetric) and decrements both endpoint degrees.
__global__ __launch_bounds__(64) void k5_dilate(
        const uint16_t* __restrict__ cols, const uint32_t* __restrict__ mateg,
        const uint32_t* __restrict__ rowptr, const uint32_t* __restrict__ deg0,
        const int* __restrict__ mask, uint32_t* __restrict__ aliveg,
        uint32_t* __restrict__ degf) {
    int b = blockIdx.x, lane = threadIdx.x;
    __shared__ uint32_t aliveW[E32];   // 16KB
    __shared__ uint32_t degc[N_];      // 8KB
    __shared__ uint8_t  mk[N_];        // 2KB
    const uint16_t* cb  = cols  + (size_t)b * EMAX;
    const uint32_t* mb  = mateg + (size_t)b * EMAX;
    const uint32_t* rpg = rowptr + (size_t)b * RPS;
    for (int i = lane; i < E32; i += 64) aliveW[i] = 0xFFFFFFFFu;
    for (int i = lane; i < N_; i += 64) {
        degc[i] = deg0[b * N_ + i];
        mk[i]   = (uint8_t)(mask[b * N_ + i] != 0);
    }
    __syncthreads();

    // rowptr pipeline in registers; prefetch next row's first-chunk cols/mates.
    uint32_t st  = 0;
    uint32_t rpA = rpg[1];
    uint32_t rpB = rpg[2];
    int pe0 = (int)st + lane;
    uint16_t c_pre = (pe0 < (int)rpA) ? cb[pe0] : (uint16_t)0;
    uint32_t m_pre = (pe0 < (int)rpA) ? mb[pe0] : 0u;

    for (int n = 0; n < N_; ++n) {
        int i3 = n + 3; if (i3 > N_) i3 = N_;
        uint32_t rpC = rpg[i3];                       // rp[n+3] for next iter
        int pe = (int)rpA + lane;                     // prefetch row n+1 chunk0
        bool pv = pe < (int)rpB;
        uint16_t c_nxt = pv ? cb[pe] : (uint16_t)0;
        uint32_t m_nxt = pv ? mb[pe] : 0u;

        uint32_t deg = degc[n];
        if (mk[n] && deg > 1u) {
            bool all = (deg <= (uint32_t)TDIL);       // sf==1 -> remove all
            uint32_t sf = (deg + 1u) >> 1;            // ceil(deg/2)
            uint32_t r2 = (deg & 1u) ? 0xFFFFFFFFu : deg;
            uint32_t running = 0;
            uint16_t cc = c_pre; uint32_t mm = m_pre;
            for (uint32_t base = st; base < rpA; base += 64) {
                uint32_t e = base + lane;
                bool inb = e < rpA;
                if (base != st) {                     // later chunks: load inline (rare)
                    cc = inb ? cb[e] : (uint16_t)0;
                    mm = inb ? mb[e] : 0u;
                }
                bool a = inb && ((aliveW[e >> 5] >> (e & 31)) & 1u);
                unsigned long long bal = __ballot(a);
                uint32_t below = (uint32_t)__popcll(bal & ((1ULL << lane) - 1ULL));
                uint32_t rank = running + below + 1u;
                if (a && (all || rank == sf || rank == r2)) {
                    atomicAnd(&aliveW[e >> 5],  ~(1u << (e & 31)));
                    atomicAnd(&aliveW[mm >> 5], ~(1u << (mm & 31)));
                    atomicSub(&degc[cc], 1u);
                }
                running += (uint32_t)__popcll(bal);
                if (!all && running >= deg) break;
            }
            if (lane == 0) degc[n] = all ? 0u : (deg - 2u + (deg & 1u));
        }
        st = rpA; rpA = rpB; rpB = rpC;
        c_pre = c_nxt; m_pre = m_nxt;
    }
    __syncthreads();
    for (int i = lane; i < E32; i += 64) aliveg[(size_t)b * E32 + i] = aliveW[i];
    for (int i = lane; i < N_; i += 64) degf[b * N_ + i] = degc[i];
}

// ---------------- K6: compact surviving cols in place ----------------
__global__ __launch_bounds__(256) void k6_compact(uint16_t* __restrict__ cols,
        const uint32_t* __restrict__ rowptr, const uint32_t* __restrict__ aliveg) {
    int row  = blockIdx.x * 4 + (threadIdx.x >> 6);
    int lane = threadIdx.x & 63;
    int b = row >> 11, n = row & (N_ - 1);
    uint16_t* cb = cols + (size_t)b * EMAX;
    const uint32_t* av = aliveg + (size_t)b * E32;
    uint32_t start = rowptr[(size_t)b * RPS + n], end = rowptr[(size_t)b * RPS + n + 1];
    uint32_t running = 0;
    for (uint32_t base = start; base < end; base += 64) {
        uint32_t e = base + lane;
        bool inb = e < end;
        uint16_t col = inb ? cb[e] : (uint16_t)0;
        bool a = inb && ((av[e >> 5] >> (e & 31)) & 1u);
        unsigned long long bal = __ballot(a);
        uint32_t below = (uint32_t)__popcll(bal & ((1ULL << lane) - 1ULL));
        if (a) cb[start + running + below] = col;     // write pos <= read pos: safe
        running += (uint32_t)__popcll(bal);
    }
}

// ---------------- K7: SpMM mean-aggregate (1 wave per row) ----------------
__global__ __launch_bounds__(256) void k7_spmm(const float* __restrict__ X,
        const uint16_t* __restrict__ cols, const uint32_t* __restrict__ rowptr,
        const uint32_t* __restrict__ degf, float* __restrict__ agg) {
    int wid  = blockIdx.x * 4 + (threadIdx.x >> 6);
    int lane = threadIdx.x & 63;
    int b = wid >> 11, n = wid & (N_ - 1);
    const uint16_t* cb = cols + (size_t)b * EMAX;
    uint32_t start = rowptr[(size_t)b * RPS + n];
    uint32_t cnt = degf[wid];
    const float* Xb = X + ((size_t)b * N_) * D_;
    float ax = 0.f, ay = 0.f;
    for (uint32_t base = 0; base < cnt; base += 64) {
        int idx = (int)base + lane;
        int cl = (idx < (int)cnt) ? (int)cb[start + idx] : 0;
        int kmax = (int)cnt - (int)base; if (kmax > 64) kmax = 64;
        for (int k = 0; k < kmax; ++k) {
            int c = __shfl(cl, k);
            float2 v = ((const float2*)(Xb + (size_t)c * D_))[lane];
            ax += v.x; ay += v.y;
        }
    }
    float inv = 1.0f / (float)(cnt ? cnt : 1u);
    ((float2*)(agg + (size_t)wid * D_))[lane] = make_float2(ax * inv, ay * inv);
}

// ---------------- K8: sage GEMM + bias + L2norm + mask + relu + BN partials ----------------
__global__ __launch_bounds__(256) void k8_gemm(const float* __restrict__ agg,
        const float* __restrict__ X, const float* __restrict__ Wr,
        const float* __restrict__ Wx, const float* __restrict__ bias,
        const int* __restrict__ mask, float* __restrict__ P,
        float* __restrict__ bnstat) {
    __shared__ float aL[32 * 128];
    __shared__ float xL[32 * 128];
    int tid = threadIdx.x;
    size_t row0 = (size_t)blockIdx.x * 32;
    for (int t = tid * 4; t < 32 * 128; t += 1024) {
        *(float4*)&aL[t] = *(const float4*)&agg[row0 * 128 + t];
        *(float4*)&xL[t] = *(const float4*)&X[row0 * 128 + t];
    }
    __syncthreads();
    int h = tid >> 6;                 // wave id 0..3 -> rows h*8..h*8+7
    int c0 = (tid & 63) * 2;
    float2 acc[8];
    #pragma unroll
    for (int i = 0; i < 8; ++i) acc[i] = make_float2(0.f, 0.f);
    for (int k4 = 0; k4 < 128; k4 += 4) {
        float2 wr[4], wx[4];
        #pragma unroll
        for (int kk = 0; kk < 4; ++kk) {
            wr[kk] = *(const float2*)&Wr[(k4 + kk) * 128 + c0];
            wx[kk] = *(const float2*)&Wx[(k4 + kk) * 128 + c0];
        }
        #pragma unroll
        for (int i = 0; i < 8; ++i) {
            int r = h * 8 + i;
            float4 a4 = *(const float4*)&aL[r * 128 + k4];
            float4 x4 = *(const float4*)&xL[r * 128 + k4];
            acc[i].x += a4.x * wr[0].x + a4.y * wr[1].x + a4.z * wr[2].x + a4.w * wr[3].x
                      + x4.x * wx[0].x + x4.y * wx[1].x + x4.z * wx[2].x + x4.w * wx[3].x;
            acc[i].y += a4.x * wr[0].y + a4.y * wr[1].y + a4.z * wr[2].y + a4.w * wr[3].y
                      + x4.x * wx[0].y + x4.y * wx[1].y + x4.z * wx[2].y + x4.w * wx[3].y;
        }
    }
    float b0 = bias[c0], b1v = bias[c0 + 1];
    __syncthreads();                  // done reading aL/xL
    #pragma unroll
    for (int i = 0; i < 8; ++i) {
        int r = h * 8 + i;
        aL[r * 128 + c0]     = acc[i].x + b0;
        aL[r * 128 + c0 + 1] = acc[i].y + b1v;
    }
    __syncthreads();
    int lane = tid & 63;
    #pragma unroll
    for (int i = 0; i < 8; ++i) {
        int r = h * 8 + i;
        float v0 = aL[r * 128 + lane], v1 = aL[r * 128 + lane + 64];
        float s = v0 * v0 + v1 * v1;
        #pragma unroll
        for (int off = 32; off >= 1; off >>= 1) s += __shfl_xor(s, off);
        float nrm = fmaxf(sqrtf(s), 1e-12f);
        float mf = (mask[row0 + r] != 0) ? 1.f : 0.f;
        float inv = mf / nrm;
        float p0 = fmaxf(v0 * inv, 0.f), p1 = fmaxf(v1 * inv, 0.f);
        P[(row0 + r) * 128 + lane]      = p0;
        P[(row0 + r) * 128 + lane + 64] = p1;
        aL[r * 128 + lane] = p0; aL[r * 128 + lane + 64] = p1;
    }
    __syncthreads();
    if (tid < 128) {
        float s = 0.f, q = 0.f;
        #pragma unroll
        for (int r = 0; r < 32; ++r) { float v = aL[r * 128 + tid]; s += v; q += v * v; }
        atomicAdd(&bnstat[tid], s);
        atomicAdd(&bnstat[128 + tid], q);
    }
}

// ---------------- K10: BatchNorm apply (training stats, biased var), in place ----------------
__global__ __launch_bounds__(256) void k10_bn(float* __restrict__ P,
        const float* __restrict__ bn, const float* __restrict__ g,
        const float* __restrict__ be) {
    int c = threadIdx.x & 127;
    int half = threadIdx.x >> 7;
    size_t base = (size_t)blockIdx.x * 16;
    float mean = bn[c] * (1.f / 16384.f);
    float var  = bn[128 + c] * (1.f / 16384.f) - mean * mean;
    float sc = g[c] * rsqrtf(var + 1e-5f);
    float sh = be[c] - mean * sc;
    for (int r = half; r < 16; r += 2) {
        size_t i = (base + r) * 128 + c;
        P[i] = P[i] * sc + sh;
    }
}

// ---------------- K11: final (concat * mf) @ Wl + bl, * mf ----------------
__global__ __launch_bounds__(256) void k11_final(const float* __restrict__ h1,
        const float* __restrict__ h2, const float* __restrict__ h3,
        const float* __restrict__ Wl, const float* __restrict__ bl,
        const int* __restrict__ mask, float* __restrict__ out) {
    __shared__ float s1[32 * 128], s2[32 * 128], s3[32 * 128];
    int tid = threadIdx.x;
    size_t row0 = (size_t)blockIdx.x * 32;
    for (int t = tid * 4; t < 32 * 128; t += 1024) {
        int r = t >> 7;
        float mf = (mask[row0 + r] != 0) ? 1.f : 0.f;
        float4 a = *(const float4*)&h1[row0 * 128 + t];
        float4 b = *(const float4*)&h2[row0 * 128 + t];
        float4 c = *(const float4*)&h3[row0 * 128 + t];
        a.x *= mf; a.y *= mf; a.z *= mf; a.w *= mf;
        b.x *= mf; b.y *= mf; b.z *= mf; b.w *= mf;
        c.x *= mf; c.y *= mf; c.z *= mf; c.w *= mf;
        *(float4*)&s1[t] = a; *(float4*)&s2[t] = b; *(float4*)&s3[t] = c;
    }
    __syncthreads();
    int h = tid >> 6, c0 = (tid & 63) * 2;
    float2 acc[8];
    #pragma unroll
    for (int i = 0; i < 8; ++i) acc[i] = make_float2(0.f, 0.f);
    for (int k4 = 0; k4 < 128; k4 += 4) {
        float2 w1[4], w2[4], w3[4];
        #pragma unroll
        for (int kk = 0; kk < 4; ++kk) {
            w1[kk] = *(const float2*)&Wl[(k4 + kk) * 128 + c0];
            w2[kk] = *(const float2*)&Wl[(128 + k4 + kk) * 128 + c0];
            w3[kk] = *(const float2*)&Wl[(256 + k4 + kk) * 128 + c0];
        }
        #pragma unroll
        for (int i = 0; i < 8; ++i) {
            int r = h * 8 + i;
            float4 a = *(const float4*)&s1[r * 128 + k4];
            float4 b = *(const float4*)&s2[r * 128 + k4];
            float4 c = *(const float4*)&s3[r * 128 + k4];
            acc[i].x += a.x * w1[0].x + a.y * w1[1].x + a.z * w1[2].x + a.w * w1[3].x
                      + b.x * w2[0].x + b.y * w2[1].x + b.z * w2[2].x + b.w * w2[3].x
                      + c.x * w3[0].x + c.y * w3[1].x + c.z * w3[2].x + c.w * w3[3].x;
            acc[i].y += a.x * w1[0].y + a.y * w1[1].y + a.z * w1[2].y + a.w * w1[3].y
                      + b.x * w2[0].y + b.y * w2[1].y + b.z * w2[2].y + b.w * w2[3].y
                      + c.x * w3[0].y + c.y * w3[1].y + c.z * w3[2].y + c.w * w3[3].y;
        }
    }
    float bx = bl[c0], by = bl[c0 + 1];
    #pragma unroll
    for (int i = 0; i < 8; ++i) {
        int r = h * 8 + i;
        float mf = (mask[row0 + r] != 0) ? 1.f : 0.f;
        *(float2*)&out[(row0 + r) * 128 + c0] =
            make_float2((acc[i].x + bx) * mf, (acc[i].y + by) * mf);
    }
}

// ---------------- launch ----------------
extern "C" void kernel_launch(void* const* d_in, const int* in_sizes, int n_in,
                              void* d_out, int out_size, void* d_ws, size_t ws_size,
                              hipStream_t stream) {
    (void)in_sizes; (void)n_in; (void)out_size; (void)ws_size;
    const float* x    = (const float*)d_in[0];
    const float* adj  = (const float*)d_in[1];
    const int*   mask = (const int*)d_in[2];
    const float* Wr1 = (const float*)d_in[3],  *Wx1 = (const float*)d_in[4];
    const float* b1  = (const float*)d_in[5],  *g1  = (const float*)d_in[6],  *be1 = (const float*)d_in[7];
    const float* Wr2 = (const float*)d_in[8],  *Wx2 = (const float*)d_in[9];
    const float* b2  = (const float*)d_in[10], *g2  = (const float*)d_in[11], *be2 = (const float*)d_in[12];
    const float* Wr3 = (const float*)d_in[13], *Wx3 = (const float*)d_in[14];
    const float* b3  = (const float*)d_in[15], *g3  = (const float*)d_in[16], *be3 = (const float*)d_in[17];
    const float* Wl  = (const float*)d_in[18], *bl  = (const float*)d_in[19];

    char* ws = (char*)d_ws;
    uint32_t* bitset = (uint32_t*)(ws + OFF_BITSET);
    float*    agg    = (float*)(ws + OFF_AGG);
    float*    h1     = (float*)(ws + OFF_H1);
    float*    h2     = (float*)(ws + OFF_H2);
    float*    h3     = (float*)(ws + OFF_H3);
    uint16_t* cols   = (uint16_t*)(ws + OFF_COLS);
    uint32_t* mate   = (uint32_t*)(ws + OFF_MATE);
    uint32_t* rp     = (uint32_t*)(ws + OFF_RP);
    uint32_t* deg0   = (uint32_t*)(ws + OFF_DEG0);
    uint32_t* degf   = (uint32_t*)(ws + OFF_DEGF);
    uint32_t* alive  = (uint32_t*)(ws + OFF_ALIVE);
    float*    bn     = (float*)(ws + OFF_BN);
    float*    out    = (float*)d_out;

    k0_zero  <<<1,    256, 0, stream>>>(bn);
    k1_bitset<<<4096, 256, 0, stream>>>(adj, bitset, deg0);
    k2_rowptr<<<8,    256, 0, stream>>>(deg0, rp);
    k3_cols  <<<4096, 256, 0, stream>>>(bitset, rp, cols);
    k4_mate  <<<4096, 256, 0, stream>>>(cols, rp, mate);
    k5_dilate<<<8,    64,  0, stream>>>(cols, mate, rp, deg0, mask, alive, degf);
    k6_compact<<<4096,256, 0, stream>>>(cols, rp, alive);
    // layer 1
    k7_spmm  <<<4096, 256, 0, stream>>>(x,  cols, rp, degf, agg);
    k8_gemm  <<<512,  256, 0, stream>>>(agg, x,  Wr1, Wx1, b1, mask, h1, bn + 0);
    k10_bn   <<<1024, 256, 0, stream>>>(h1, bn + 0,   g1, be1);
    // layer 2
    k7_spmm  <<<4096, 256, 0, stream>>>(h1, cols, rp, degf, agg);
    k8_gemm  <<<512,  256, 0, stream>>>(agg, h1, Wr2, Wx2, b2, mask, h2, bn + 256);
    k10_bn   <<<1024, 256, 0, stream>>>(h2, bn + 256, g2, be2);
    // layer 3
    k7_spmm  <<<4096, 256, 0, stream>>>(h2, cols, rp, degf, agg);
    k8_gemm  <<<512,  256, 0, stream>>>(agg, h2, Wr3, Wx3, b3, mask, h3, bn + 512);
    k10_bn   <<<1024, 256, 0, stream>>>(h3, bn + 512, g3, be3);
    // final
    k11_final<<<512,  256, 0, stream>>>(h1, h2, h3, Wl, bl, mask, out);
}

// Round 2
// 1150.023 us; speedup vs baseline: 1.0246x; 1.0246x over previous
//
#include <hip/hip_runtime.h>
#include <cstdint>

// ---------------- problem constants ----------------
constexpr int B_ = 8, N_ = 2048, D_ = 128, NW = 64;   // NW = words per bitset row
constexpr int EMAX = 131072;                           // per-batch edge capacity
constexpr int RPS = 2064;                              // rowptr stride per batch
constexpr int TDIL = 10;

// ---------------- workspace layout (bytes) ----------------
constexpr size_t OFF_BITSET = 0;                  // 4MB (preproc), reused as agg (8MB)
constexpr size_t OFF_AGG    = 0;
constexpr size_t OFF_H1     = (size_t)8  << 20;
constexpr size_t OFF_H2     = (size_t)16 << 20;
constexpr size_t OFF_H3     = (size_t)24 << 20;
constexpr size_t OFF_COLS   = (size_t)32 << 20;   // u16 [B][EMAX]  (2MB)
constexpr size_t OFF_PACKED = (size_t)34 << 20;   // u32 [B][EMAX]  (4MB): col | mlocal<<16
constexpr size_t OFF_RP     = (size_t)38 << 20;   // u32 [B][RPS]
constexpr size_t OFF_DEG0   = OFF_RP   + ((size_t)128 << 10);
constexpr size_t OFF_DEGF   = OFF_DEG0 + ((size_t)64  << 10);
constexpr size_t OFF_RMASK  = OFF_DEGF + ((size_t)64  << 10);  // u32 [B][N][4] (256KB)
constexpr size_t OFF_BN     = OFF_RMASK + ((size_t)256 << 10); // 3*256 floats

// ---------------- K0: zero BN stats ----------------
__global__ void k0_zero(float* bn) {
    for (int i = threadIdx.x; i < 768; i += 256) bn[i] = 0.f;
}

// ---------------- K1: adj (fp32 0/1) -> bitset + degrees ----------------
__global__ __launch_bounds__(256) void k1_bitset(const float* __restrict__ adj,
        uint32_t* __restrict__ bitset, uint32_t* __restrict__ deg0) {
    int row  = blockIdx.x * 4 + (threadIdx.x >> 6);
    int lane = threadIdx.x & 63;
    const float* ar = adj + (size_t)row * N_;
    uint32_t myw = 0;
    #pragma unroll 4
    for (int it = 0; it < 32; ++it) {
        float v = ar[it * 64 + lane];
        unsigned long long m = __ballot(v != 0.0f);
        if (lane == 2 * it)          myw = (uint32_t)m;
        else if (lane == 2 * it + 1) myw = (uint32_t)(m >> 32);
    }
    bitset[(size_t)row * NW + lane] = myw;
    int pc = __popc(myw);
    #pragma unroll
    for (int off = 32; off >= 1; off >>= 1) pc += __shfl_xor(pc, off);
    if (lane == 0) deg0[row] = (uint32_t)pc;
}

// ---------------- K2: per-batch prefix sum of degrees -> rowptr ----------------
__global__ __launch_bounds__(256) void k2_rowptr(const uint32_t* __restrict__ deg0,
        uint32_t* __restrict__ rowptr) {
    int b = blockIdx.x, t = threadIdx.x;
    __shared__ uint32_t tsum[256];
    uint32_t v[8]; uint32_t s = 0;
    #pragma unroll
    for (int j = 0; j < 8; ++j) { v[j] = deg0[b * N_ + t * 8 + j]; s += v[j]; v[j] = s; }
    tsum[t] = s;
    __syncthreads();
    for (int off = 1; off < 256; off <<= 1) {
        uint32_t xv = (t >= off) ? tsum[t - off] : 0u;
        __syncthreads();
        tsum[t] += xv;
        __syncthreads();
    }
    uint32_t excl = tsum[t] - s;
    uint32_t* rp = rowptr + (size_t)b * RPS;
    if (t == 0) rp[0] = 0;
    #pragma unroll
    for (int j = 0; j < 8; ++j) {
        uint32_t val = excl + v[j];
        if (val > (uint32_t)EMAX) val = EMAX;   // safety clamp
        rp[t * 8 + j + 1] = val;
    }
}

// ---------------- K3: fill sorted column lists ----------------
__global__ __launch_bounds__(256) void k3_cols(const uint32_t* __restrict__ bitset,
        const uint32_t* __restrict__ rowptr, uint16_t* __restrict__ cols) {
    int row  = blockIdx.x * 4 + (threadIdx.x >> 6);
    int lane = threadIdx.x & 63;
    int b = row >> 11, n = row & (N_ - 1);
    uint32_t w = bitset[(size_t)row * NW + lane];
    uint32_t pc = __popc(w);
    uint32_t inc = pc;
    #pragma unroll
    for (int off = 1; off < 64; off <<= 1) {
        uint32_t t = __shfl_up(inc, off);
        if (lane >= off) inc += t;
    }
    uint32_t base = rowptr[(size_t)b * RPS + n] + (inc - pc);
    uint16_t* cb = cols + (size_t)b * EMAX;
    while (w) {
        int bit = __builtin_ctz(w); w &= w - 1;
        if (base < (uint32_t)EMAX) cb[base] = (uint16_t)(lane * 32 + bit);
        ++base;
    }
}

// ---------------- K4: packed (col | mate_local<<16) via binary search ----------------
__global__ __launch_bounds__(256) void k4_packed(const uint16_t* __restrict__ cols,
        const uint32_t* __restrict__ rowptr, uint32_t* __restrict__ packed) {
    int row  = blockIdx.x * 4 + (threadIdx.x >> 6);
    int lane = threadIdx.x & 63;
    int b = row >> 11, n = row & (N_ - 1);
    const uint32_t* rpb = rowptr + (size_t)b * RPS;
    const uint16_t* cb  = cols + (size_t)b * EMAX;
    uint32_t start = rpb[n], end = rpb[n + 1];
    for (uint32_t e = start + lane; e < end; e += 64) {
        uint32_t j = cb[e];
        uint32_t lo = rpb[j], hi = rpb[j + 1];
        uint32_t rj = lo;
        while (lo < hi) {
            uint32_t mid = (lo + hi) >> 1;
            if ((int)cb[mid] < n) lo = mid + 1; else hi = mid;
        }
        packed[(size_t)b * EMAX + e] = j | ((lo - rj) << 16);
    }
}

// ---------------- K5: sequential dilation (1 wave per batch) ----------------
// Per-row 128-bit alive mask over ORIGINAL neighbor ranks. Per row n (in order):
//   num = popc(mask); if mask_b[n] && num>1: remove ranks {sf, 2sf<=num} (sf=ceil(num/2))
//   or ALL if num<=T_DIL. Symmetric removal = atomicAnd bit mate_local in row col's mask.
// Relies on per-wave in-order LDS completion: next row's mask read is issued after
// this row's atomics in program order, so it observes them.
__global__ __launch_bounds__(64) void k5_dilate(
        const uint32_t* __restrict__ packed, const uint32_t* __restrict__ rowptr,
        const uint32_t* __restrict__ deg0, const int* __restrict__ mask,
        uint32_t* __restrict__ rmaskg, uint32_t* __restrict__ degf) {
    int b = blockIdx.x, lane = threadIdx.x;
    __shared__ __align__(16) uint32_t rm4[N_ * 4];   // 32KB
    __shared__ uint32_t rps[N_ + 1];                 // 8.2KB
    __shared__ uint8_t  mk[N_];                      // 2KB
    const uint32_t* pk  = packed + (size_t)b * EMAX;
    const uint32_t* rpg = rowptr + (size_t)b * RPS;

    for (int i = lane; i <= N_; i += 64) rps[i] = rpg[i];
    for (int i = lane; i < N_; i += 64) {
        int d = (int)deg0[b * N_ + i]; if (d > 128) d = 128;
        uint4 mm;
        mm.x = (d >= 32) ? ~0u : ((d > 0)  ? ((1u << d)        - 1u) : 0u);
        mm.y = (d >= 64) ? ~0u : ((d > 32) ? ((1u << (d - 32)) - 1u) : 0u);
        mm.z = (d >= 96) ? ~0u : ((d > 64) ? ((1u << (d - 64)) - 1u) : 0u);
        mm.w = (d >= 128)? ~0u : ((d > 96) ? ((1u << (d - 96)) - 1u) : 0u);
        *(uint4*)&rm4[(size_t)i * 4] = mm;
        mk[i] = (uint8_t)(mask[b * N_ + i] != 0);
    }
    __syncthreads();

    // prologue: row 0 mask; packed for rows 0,1; rp/mk pipelines
    uint4 mcur = *(const uint4*)&rm4[0];
    uint8_t mkc = mk[0], mkn = mk[1];
    uint32_t en0 = rps[1], en1 = rps[2], rp_n3 = rps[3];
    uint32_t rp_n2 = en1;                       // rps[n+2] for n=0
    uint32_t pkA0 = (lane < (int)en0) ? pk[lane] : 0;
    uint32_t pkA1 = (lane + 64 < (int)en0) ? pk[lane + 64] : 0;
    uint32_t lenB = en1 - en0;
    uint32_t pkB0 = ((uint32_t)lane < lenB) ? pk[en0 + lane] : 0;
    uint32_t pkB1 = ((uint32_t)lane + 64u < lenB) ? pk[en0 + 64 + lane] : 0;
    unsigned long long below = (1ULL << lane) - 1ULL;

    for (int n = 0; n < N_; ++n) {
        // --- prefetch static data for row n+2 ---
        int i4 = n + 4; if (i4 > N_) i4 = N_;
        uint32_t rpNew = rps[i4];                       // rps[n+4]
        uint32_t lenC = rp_n3 - rp_n2;
        uint32_t pkC0 = ((uint32_t)lane < lenC) ? pk[rp_n2 + lane] : 0;
        uint32_t pkC1 = ((uint32_t)lane + 64u < lenC) ? pk[rp_n2 + 64 + lane] : 0;
        int imk = n + 2; if (imk >= N_) imk = N_ - 1;
        uint8_t mkq = mk[imk];

        // --- process row n ---
        uint32_t w01 = (lane < 32) ? mcur.x : mcur.y;
        uint32_t w23 = (lane < 32) ? mcur.z : mcur.w;
        uint32_t a0 = (w01 >> (lane & 31)) & 1u;
        uint32_t a1 = (w23 >> (lane & 31)) & 1u;
        unsigned long long b0 = __ballot(a0 != 0), b1 = __ballot(a1 != 0);
        uint32_t num = (uint32_t)__popcll(b0) + (uint32_t)__popcll(b1);
        if (mkc && num > 1u) {
            bool allrm = num <= (uint32_t)TDIL;         // sf==1 -> remove all
            uint32_t sf = (num + 1u) >> 1;              // ceil(num/2)
            uint32_t r2 = (num & 1u) ? 0xFFFFFFFFu : num;
            uint32_t rank0 = (uint32_t)__popcll(b0 & below) + 1u;
            uint32_t rank1 = (uint32_t)__popcll(b0) + (uint32_t)__popcll(b1 & below) + 1u;
            bool rm0 = a0 && (allrm || rank0 == sf || rank0 == r2);
            bool rm1 = a1 && (allrm || rank1 == sf || rank1 == r2);
            unsigned long long rb0 = __ballot(rm0), rb1 = __ballot(rm1);
            if (rm0) {
                uint32_t c = pkA0 & 0xFFFFu, ml = pkA0 >> 16;
                if (ml < 128u) atomicAnd(&rm4[c * 4 + (ml >> 5)], ~(1u << (ml & 31)));
            }
            if (rm1) {
                uint32_t c = pkA1 & 0xFFFFu, ml = pkA1 >> 16;
                if (ml < 128u) atomicAnd(&rm4[c * 4 + (ml >> 5)], ~(1u << (ml & 31)));
            }
            if (lane == 0) {
                uint4 nm;
                nm.x = mcur.x & ~(uint32_t)rb0;
                nm.y = mcur.y & ~(uint32_t)(rb0 >> 32);
                nm.z = mcur.z & ~(uint32_t)rb1;
                nm.w = mcur.w & ~(uint32_t)(rb1 >> 32);
                *(uint4*)&rm4[(size_t)n * 4] = nm;
            }
        }
        // --- read next row's mask (after atomics; in-order DS) ---
        if (n + 1 < N_) mcur = *(const uint4*)&rm4[(size_t)(n + 1) * 4];
        // --- shift pipelines ---
        pkA0 = pkB0; pkA1 = pkB1; pkB0 = pkC0; pkB1 = pkC1;
        mkc = mkn; mkn = mkq;
        rp_n2 = rp_n3; rp_n3 = rpNew;
    }
    __syncthreads();
    for (int i = lane; i < N_; i += 64) {
        uint4 mm = *(const uint4*)&rm4[(size_t)i * 4];
        *(uint4*)&rmaskg[((size_t)b * N_ + i) * 4] = mm;
        degf[b * N_ + i] = (uint32_t)(__popc(mm.x) + __popc(mm.y) + __popc(mm.z) + __popc(mm.w));
    }
}

// ---------------- K6: compact surviving cols in place (from rank masks) ----------------
__global__ __launch_bounds__(256) void k6_compact(uint16_t* __restrict__ cols,
        const uint32_t* __restrict__ rowptr, const uint32_t* __restrict__ rmaskg) {
    int row  = blockIdx.x * 4 + (threadIdx.x >> 6);
    int lane = threadIdx.x & 63;
    int b = row >> 11, n = row & (N_ - 1);
    uint16_t* cb = cols + (size_t)b * EMAX;
    uint4 mm = *(const uint4*)&rmaskg[(size_t)row * 4];
    uint32_t st = rowptr[(size_t)b * RPS + n];
    uint32_t w01 = (lane < 32) ? mm.x : mm.y;
    uint32_t w23 = (lane < 32) ? mm.z : mm.w;
    uint32_t a0 = (w01 >> (lane & 31)) & 1u;
    uint32_t a1 = (w23 >> (lane & 31)) & 1u;
    unsigned long long b0 = __ballot(a0 != 0), b1 = __ballot(a1 != 0);
    unsigned long long below = (1ULL << lane) - 1ULL;
    uint16_t c0v = 0, c1v = 0;
    if (a0) c0v = cb[st + lane];
    if (a1) c1v = cb[st + 64 + lane];
    uint32_t i0 = st + (uint32_t)__popcll(b0 & below);
    uint32_t i1 = st + (uint32_t)__popcll(b0) + (uint32_t)__popcll(b1 & below);
    if (a0) cb[i0] = c0v;
    if (a1) cb[i1] = c1v;
}

// ---------------- K7: SpMM mean-aggregate (1 wave per row) ----------------
__global__ __launch_bounds__(256) void k7_spmm(const float* __restrict__ X,
        const uint16_t* __restrict__ cols, const uint32_t* __restrict__ rowptr,
        const uint32_t* __restrict__ degf, float* __restrict__ agg) {
    int wid  = blockIdx.x * 4 + (threadIdx.x >> 6);
    int lane = threadIdx.x & 63;
    int b = wid >> 11, n = wid & (N_ - 1);
    const uint16_t* cb = cols + (size_t)b * EMAX;
    uint32_t start = rowptr[(size_t)b * RPS + n];
    uint32_t cnt = degf[wid];
    const float* Xb = X + ((size_t)b * N_) * D_;
    float ax = 0.f, ay = 0.f;
    for (uint32_t base = 0; base < cnt; base += 64) {
        int idx = (int)base + lane;
        int cl = (idx < (int)cnt) ? (int)cb[start + idx] : 0;
        int kmax = (int)cnt - (int)base; if (kmax > 64) kmax = 64;
        for (int k = 0; k < kmax; ++k) {
            int c = __shfl(cl, k);
            float2 v = ((const float2*)(Xb + (size_t)c * D_))[lane];
            ax += v.x; ay += v.y;
        }
    }
    float inv = 1.0f / (float)(cnt ? cnt : 1u);
    ((float2*)(agg + (size_t)wid * D_))[lane] = make_float2(ax * inv, ay * inv);
}

// ---------------- K8: sage GEMM + bias + L2norm + mask + relu + BN partials ----------------
__global__ __launch_bounds__(256) void k8_gemm(const float* __restrict__ agg,
        const float* __restrict__ X, const float* __restrict__ Wr,
        const float* __restrict__ Wx, const float* __restrict__ bias,
        const int* __restrict__ mask, float* __restrict__ P,
        float* __restrict__ bnstat) {
    __shared__ float aL[32 * 128];
    __shared__ float xL[32 * 128];
    int tid = threadIdx.x;
    size_t row0 = (size_t)blockIdx.x * 32;
    for (int t = tid * 4; t < 32 * 128; t += 1024) {
        *(float4*)&aL[t] = *(const float4*)&agg[row0 * 128 + t];
        *(float4*)&xL[t] = *(const float4*)&X[row0 * 128 + t];
    }
    __syncthreads();
    int h = tid >> 6;
    int c0 = (tid & 63) * 2;
    float2 acc[8];
    #pragma unroll
    for (int i = 0; i < 8; ++i) acc[i] = make_float2(0.f, 0.f);
    for (int k4 = 0; k4 < 128; k4 += 4) {
        float2 wr[4], wx[4];
        #pragma unroll
        for (int kk = 0; kk < 4; ++kk) {
            wr[kk] = *(const float2*)&Wr[(k4 + kk) * 128 + c0];
            wx[kk] = *(const float2*)&Wx[(k4 + kk) * 128 + c0];
        }
        #pragma unroll
        for (int i = 0; i < 8; ++i) {
            int r = h * 8 + i;
            float4 a4 = *(const float4*)&aL[r * 128 + k4];
            float4 x4 = *(const float4*)&xL[r * 128 + k4];
            acc[i].x += a4.x * wr[0].x + a4.y * wr[1].x + a4.z * wr[2].x + a4.w * wr[3].x
                      + x4.x * wx[0].x + x4.y * wx[1].x + x4.z * wx[2].x + x4.w * wx[3].x;
            acc[i].y += a4.x * wr[0].y + a4.y * wr[1].y + a4.z * wr[2].y + a4.w * wr[3].y
                      + x4.x * wx[0].y + x4.y * wx[1].y + x4.z * wx[2].y + x4.w * wx[3].y;
        }
    }
    float b0 = bias[c0], b1v = bias[c0 + 1];
    __syncthreads();
    #pragma unroll
    for (int i = 0; i < 8; ++i) {
        int r = h * 8 + i;
        aL[r * 128 + c0]     = acc[i].x + b0;
        aL[r * 128 + c0 + 1] = acc[i].y + b1v;
    }
    __syncthreads();
    int lane = tid & 63;
    #pragma unroll
    for (int i = 0; i < 8; ++i) {
        int r = h * 8 + i;
        float v0 = aL[r * 128 + lane], v1 = aL[r * 128 + lane + 64];
        float s = v0 * v0 + v1 * v1;
        #pragma unroll
        for (int off = 32; off >= 1; off >>= 1) s += __shfl_xor(s, off);
        float nrm = fmaxf(sqrtf(s), 1e-12f);
        float mf = (mask[row0 + r] != 0) ? 1.f : 0.f;
        float inv = mf / nrm;
        float p0 = fmaxf(v0 * inv, 0.f), p1 = fmaxf(v1 * inv, 0.f);
        P[(row0 + r) * 128 + lane]      = p0;
        P[(row0 + r) * 128 + lane + 64] = p1;
        aL[r * 128 + lane] = p0; aL[r * 128 + lane + 64] = p1;
    }
    __syncthreads();
    if (tid < 128) {
        float s = 0.f, q = 0.f;
        #pragma unroll
        for (int r = 0; r < 32; ++r) { float v = aL[r * 128 + tid]; s += v; q += v * v; }
        atomicAdd(&bnstat[tid], s);
        atomicAdd(&bnstat[128 + tid], q);
    }
}

// ---------------- K10: BatchNorm apply (training stats, biased var), in place ----------------
__global__ __launch_bounds__(256) void k10_bn(float* __restrict__ P,
        const float* __restrict__ bn, const float* __restrict__ g,
        const float* __restrict__ be) {
    int c = threadIdx.x & 127;
    int half = threadIdx.x >> 7;
    size_t base = (size_t)blockIdx.x * 16;
    float mean = bn[c] * (1.f / 16384.f);
    float var  = bn[128 + c] * (1.f / 16384.f) - mean * mean;
    float sc = g[c] * rsqrtf(var + 1e-5f);
    float sh = be[c] - mean * sc;
    for (int r = half; r < 16; r += 2) {
        size_t i = (base + r) * 128 + c;
        P[i] = P[i] * sc + sh;
    }
}

// ---------------- K11: final (concat * mf) @ Wl + bl, * mf ----------------
__global__ __launch_bounds__(256) void k11_final(const float* __restrict__ h1,
        const float* __restrict__ h2, const float* __restrict__ h3,
        const float* __restrict__ Wl, const float* __restrict__ bl,
        const int* __restrict__ mask, float* __restrict__ out) {
    __shared__ float s1[32 * 128], s2[32 * 128], s3[32 * 128];
    int tid = threadIdx.x;
    size_t row0 = (size_t)blockIdx.x * 32;
    for (int t = tid * 4; t < 32 * 128; t += 1024) {
        int r = t >> 7;
        float mf = (mask[row0 + r] != 0) ? 1.f : 0.f;
        float4 a = *(const float4*)&h1[row0 * 128 + t];
        float4 b = *(const float4*)&h2[row0 * 128 + t];
        float4 c = *(const float4*)&h3[row0 * 128 + t];
        a.x *= mf; a.y *= mf; a.z *= mf; a.w *= mf;
        b.x *= mf; b.y *= mf; b.z *= mf; b.w *= mf;
        c.x *= mf; c.y *= mf; c.z *= mf; c.w *= mf;
        *(float4*)&s1[t] = a; *(float4*)&s2[t] = b; *(float4*)&s3[t] = c;
    }
    __syncthreads();
    int h = tid >> 6, c0 = (tid & 63) * 2;
    float2 acc[8];
    #pragma unroll
    for (int i = 0; i < 8; ++i) acc[i] = make_float2(0.f, 0.f);
    for (int k4 = 0; k4 < 128; k4 += 4) {
        float2 w1[4], w2[4], w3[4];
        #pragma unroll
        for (int kk = 0; kk < 4; ++kk) {
            w1[kk] = *(const float2*)&Wl[(k4 + kk) * 128 + c0];
            w2[kk] = *(const float2*)&Wl[(128 + k4 + kk) * 128 + c0];
            w3[kk] = *(const float2*)&Wl[(256 + k4 + kk) * 128 + c0];
        }
        #pragma unroll
        for (int i = 0; i < 8; ++i) {
            int r = h * 8 + i;
            float4 a = *(const float4*)&s1[r * 128 + k4];
            float4 b = *(const float4*)&s2[r * 128 + k4];
            float4 c = *(const float4*)&s3[r * 128 + k4];
            acc[i].x += a.x * w1[0].x + a.y * w1[1].x + a.z * w1[2].x + a.w * w1[3].x
                      + b.x * w2[0].x + b.y * w2[1].x + b.z * w2[2].x + b.w * w2[3].x
                      + c.x * w3[0].x + c.y * w3[1].x + c.z * w3[2].x + c.w * w3[3].x;
            acc[i].y += a.x * w1[0].y + a.y * w1[1].y + a.z * w1[2].y + a.w * w1[3].y
                      + b.x * w2[0].y + b.y * w2[1].y + b.z * w2[2].y + b.w * w2[3].y
                      + c.x * w3[0].y + c.y * w3[1].y + c.z * w3[2].y + c.w * w3[3].y;
        }
    }
    float bx = bl[c0], by = bl[c0 + 1];
    #pragma unroll
    for (int i = 0; i < 8; ++i) {
        int r = h * 8 + i;
        float mf = (mask[row0 + r] != 0) ? 1.f : 0.f;
        *(float2*)&out[(row0 + r) * 128 + c0] =
            make_float2((acc[i].x + bx) * mf, (acc[i].y + by) * mf);
    }
}

// ---------------- launch ----------------
extern "C" void kernel_launch(void* const* d_in, const int* in_sizes, int n_in,
                              void* d_out, int out_size, void* d_ws, size_t ws_size,
                              hipStream_t stream) {
    (void)in_sizes; (void)n_in; (void)out_size; (void)ws_size;
    const float* x    = (const float*)d_in[0];
    const float* adj  = (const float*)d_in[1];
    const int*   mask = (const int*)d_in[2];
    const float* Wr1 = (const float*)d_in[3],  *Wx1 = (const float*)d_in[4];
    const float* b1  = (const float*)d_in[5],  *g1  = (const float*)d_in[6],  *be1 = (const float*)d_in[7];
    const float* Wr2 = (const float*)d_in[8],  *Wx2 = (const float*)d_in[9];
    const float* b2  = (const float*)d_in[10], *g2  = (const float*)d_in[11], *be2 = (const float*)d_in[12];
    const float* Wr3 = (const float*)d_in[13], *Wx3 = (const float*)d_in[14];
    const float* b3  = (const float*)d_in[15], *g3  = (const float*)d_in[16], *be3 = (const float*)d_in[17];
    const float* Wl  = (const float*)d_in[18], *bl  = (const float*)d_in[19];

    char* ws = (char*)d_ws;
    uint32_t* bitset = (uint32_t*)(ws + OFF_BITSET);
    float*    agg    = (float*)(ws + OFF_AGG);
    float*    h1     = (float*)(ws + OFF_H1);
    float*    h2     = (float*)(ws + OFF_H2);
    float*    h3     = (float*)(ws + OFF_H3);
    uint16_t* cols   = (uint16_t*)(ws + OFF_COLS);
    uint32_t* packed = (uint32_t*)(ws + OFF_PACKED);
    uint32_t* rp     = (uint32_t*)(ws + OFF_RP);
    uint32_t* deg0   = (uint32_t*)(ws + OFF_DEG0);
    uint32_t* degf   = (uint32_t*)(ws + OFF_DEGF);
    uint32_t* rmaskg = (uint32_t*)(ws + OFF_RMASK);
    float*    bn     = (float*)(ws + OFF_BN);
    float*    out    = (float*)d_out;

    k0_zero   <<<1,    256, 0, stream>>>(bn);
    k1_bitset <<<4096, 256, 0, stream>>>(adj, bitset, deg0);
    k2_rowptr <<<8,    256, 0, stream>>>(deg0, rp);
    k3_cols   <<<4096, 256, 0, stream>>>(bitset, rp, cols);
    k4_packed <<<4096, 256, 0, stream>>>(cols, rp, packed);
    k5_dilate <<<8,    64,  0, stream>>>(packed, rp, deg0, mask, rmaskg, degf);
    k6_compact<<<4096, 256, 0, stream>>>(cols, rp, rmaskg);
    // layer 1
    k7_spmm   <<<4096, 256, 0, stream>>>(x,  cols, rp, degf, agg);
    k8_gemm   <<<512,  256, 0, stream>>>(agg, x,  Wr1, Wx1, b1, mask, h1, bn + 0);
    k10_bn    <<<1024, 256, 0, stream>>>(h1, bn + 0,   g1, be1);
    // layer 2
    k7_spmm   <<<4096, 256, 0, stream>>>(h1, cols, rp, degf, agg);
    k8_gemm   <<<512,  256, 0, stream>>>(agg, h1, Wr2, Wx2, b2, mask, h2, bn + 256);
    k10_bn    <<<1024, 256, 0, stream>>>(h2, bn + 256, g2, be2);
    // layer 3
    k7_spmm   <<<4096, 256, 0, stream>>>(h2, cols, rp, degf, agg);
    k8_gemm   <<<512,  256, 0, stream>>>(agg, h2, Wr3, Wx3, b3, mask, h3, bn + 512);
    k10_bn    <<<1024, 256, 0, stream>>>(h3, bn + 512, g3, be3);
    // final
    k11_final <<<512,  256, 0, stream>>>(h1, h2, h3, Wl, bl, mask, out);
}

// Round 3
// 1043.761 us; speedup vs baseline: 1.1290x; 1.1018x over previous
//
#include <hip/hip_runtime.h>
#include <cstdint>

// ---------------- problem constants ----------------
constexpr int B_ = 8, N_ = 2048, D_ = 128, NW = 64;   // NW = words per bitset row
constexpr int EMAX = 131072;                           // per-batch edge capacity
constexpr int RPS = 2064;                              // rowptr stride per batch
constexpr int TDIL = 10;

// ---------------- workspace layout (bytes) ----------------
constexpr size_t OFF_BITSET = 0;                  // 4MB (preproc), reused as agg (8MB)
constexpr size_t OFF_AGG    = 0;
constexpr size_t OFF_H1     = (size_t)8  << 20;
constexpr size_t OFF_H2     = (size_t)16 << 20;
constexpr size_t OFF_H3     = (size_t)24 << 20;
constexpr size_t OFF_COLS   = (size_t)32 << 20;   // u16 [B][EMAX]  (2MB)
constexpr size_t OFF_PACKED = (size_t)34 << 20;   // u32 [B][EMAX]  (4MB): col | mlocal<<16
constexpr size_t OFF_RP     = (size_t)38 << 20;   // u32 [B][RPS]
constexpr size_t OFF_DEG0   = OFF_RP   + ((size_t)128 << 10);
constexpr size_t OFF_DEGF   = OFF_DEG0 + ((size_t)64  << 10);
constexpr size_t OFF_RMASK  = OFF_DEGF + ((size_t)64  << 10);  // u32 [B][N][4] (256KB)
constexpr size_t OFF_BN     = OFF_RMASK + ((size_t)256 << 10); // 3*256 floats

// ---------------- K0: zero BN stats ----------------
__global__ void k0_zero(float* bn) {
    for (int i = threadIdx.x; i < 768; i += 256) bn[i] = 0.f;
}

// ---------------- K1: adj (fp32 0/1) -> bitset + degrees ----------------
__global__ __launch_bounds__(256) void k1_bitset(const float* __restrict__ adj,
        uint32_t* __restrict__ bitset, uint32_t* __restrict__ deg0) {
    int row  = blockIdx.x * 4 + (threadIdx.x >> 6);
    int lane = threadIdx.x & 63;
    const float* ar = adj + (size_t)row * N_;
    uint32_t myw = 0;
    #pragma unroll 4
    for (int it = 0; it < 32; ++it) {
        float v = ar[it * 64 + lane];
        unsigned long long m = __ballot(v != 0.0f);
        if (lane == 2 * it)          myw = (uint32_t)m;
        else if (lane == 2 * it + 1) myw = (uint32_t)(m >> 32);
    }
    bitset[(size_t)row * NW + lane] = myw;
    int pc = __popc(myw);
    #pragma unroll
    for (int off = 32; off >= 1; off >>= 1) pc += __shfl_xor(pc, off);
    if (lane == 0) deg0[row] = (uint32_t)pc;
}

// ---------------- K2: per-batch prefix sum of degrees -> rowptr ----------------
__global__ __launch_bounds__(256) void k2_rowptr(const uint32_t* __restrict__ deg0,
        uint32_t* __restrict__ rowptr) {
    int b = blockIdx.x, t = threadIdx.x;
    __shared__ uint32_t tsum[256];
    uint32_t v[8]; uint32_t s = 0;
    #pragma unroll
    for (int j = 0; j < 8; ++j) { v[j] = deg0[b * N_ + t * 8 + j]; s += v[j]; v[j] = s; }
    tsum[t] = s;
    __syncthreads();
    for (int off = 1; off < 256; off <<= 1) {
        uint32_t xv = (t >= off) ? tsum[t - off] : 0u;
        __syncthreads();
        tsum[t] += xv;
        __syncthreads();
    }
    uint32_t excl = tsum[t] - s;
    uint32_t* rp = rowptr + (size_t)b * RPS;
    if (t == 0) rp[0] = 0;
    #pragma unroll
    for (int j = 0; j < 8; ++j) {
        uint32_t val = excl + v[j];
        if (val > (uint32_t)EMAX) val = EMAX;   // safety clamp
        rp[t * 8 + j + 1] = val;
    }
}

// ---------------- K3: fill sorted column lists ----------------
__global__ __launch_bounds__(256) void k3_cols(const uint32_t* __restrict__ bitset,
        const uint32_t* __restrict__ rowptr, uint16_t* __restrict__ cols) {
    int row  = blockIdx.x * 4 + (threadIdx.x >> 6);
    int lane = threadIdx.x & 63;
    int b = row >> 11, n = row & (N_ - 1);
    uint32_t w = bitset[(size_t)row * NW + lane];
    uint32_t pc = __popc(w);
    uint32_t inc = pc;
    #pragma unroll
    for (int off = 1; off < 64; off <<= 1) {
        uint32_t t = __shfl_up(inc, off);
        if (lane >= off) inc += t;
    }
    uint32_t base = rowptr[(size_t)b * RPS + n] + (inc - pc);
    uint16_t* cb = cols + (size_t)b * EMAX;
    while (w) {
        int bit = __builtin_ctz(w); w &= w - 1;
        if (base < (uint32_t)EMAX) cb[base] = (uint16_t)(lane * 32 + bit);
        ++base;
    }
}

// ---------------- K4: packed (col | mate_local<<16) via binary search ----------------
__global__ __launch_bounds__(256) void k4_packed(const uint16_t* __restrict__ cols,
        const uint32_t* __restrict__ rowptr, uint32_t* __restrict__ packed) {
    int row  = blockIdx.x * 4 + (threadIdx.x >> 6);
    int lane = threadIdx.x & 63;
    int b = row >> 11, n = row & (N_ - 1);
    const uint32_t* rpb = rowptr + (size_t)b * RPS;
    const uint16_t* cb  = cols + (size_t)b * EMAX;
    uint32_t start = rpb[n], end = rpb[n + 1];
    for (uint32_t e = start + lane; e < end; e += 64) {
        uint32_t j = cb[e];
        uint32_t lo = rpb[j], hi = rpb[j + 1];
        uint32_t rj = lo;
        while (lo < hi) {
            uint32_t mid = (lo + hi) >> 1;
            if ((int)cb[mid] < n) lo = mid + 1; else hi = mid;
        }
        packed[(size_t)b * EMAX + e] = j | ((lo - rj) << 16);
    }
}

// ---------------- async global->LDS helper (one 64-entry u32 chunk) ----------------
__device__ __forceinline__ void ld_lds_64u32(const uint32_t* gsrc, uint32_t* ldst) {
    __builtin_amdgcn_global_load_lds(
        (const __attribute__((address_space(1))) uint32_t*)(gsrc + threadIdx.x),
        (__attribute__((address_space(3))) uint32_t*)ldst, 4, 0, 0);
}

// ---------------- K5: sequential dilation (1 wave per batch) ----------------
// Per-row 128-bit alive mask over ORIGINAL neighbor ranks. Packed (col|mlocal<<16)
// entries are streamed 8 rows ahead into a 16-slot LDS ring via global_load_lds
// with counted s_waitcnt vmcnt(14) (never 0) so L3/HBM latency stays hidden.
// Relies on per-wave in-order LDS completion for atomic->read ordering.
__global__ __launch_bounds__(64) void k5_dilate(
        const uint32_t* __restrict__ packed, const uint32_t* __restrict__ rowptr,
        const uint32_t* __restrict__ deg0, const int* __restrict__ mask,
        uint32_t* __restrict__ rmaskg, uint32_t* __restrict__ degf) {
    int b = blockIdx.x, lane = threadIdx.x;
    __shared__ __align__(16) uint32_t rm4[N_ * 4];    // 32KB
    __shared__ uint32_t rps[N_ + 1];                  // 8.2KB
    __shared__ uint8_t  mk[N_];                       // 2KB
    __shared__ __align__(16) uint32_t ring[16 * 128]; // 8KB: 16 slots x 128 entries
    const uint32_t* pk  = packed + (size_t)b * EMAX;
    const uint32_t* rpg = rowptr + (size_t)b * RPS;

    for (int i = lane; i <= N_; i += 64) rps[i] = rpg[i];
    for (int i = lane; i < N_; i += 64) {
        int d = (int)deg0[b * N_ + i]; if (d > 128) d = 128;
        uint4 mm;
        mm.x = (d >= 32) ? ~0u : ((d > 0)  ? ((1u << d)        - 1u) : 0u);
        mm.y = (d >= 64) ? ~0u : ((d > 32) ? ((1u << (d - 32)) - 1u) : 0u);
        mm.z = (d >= 96) ? ~0u : ((d > 64) ? ((1u << (d - 64)) - 1u) : 0u);
        mm.w = (d >= 128)? ~0u : ((d > 96) ? ((1u << (d - 96)) - 1u) : 0u);
        *(uint4*)&rm4[(size_t)i * 4] = mm;
        mk[i] = (uint8_t)(mask[b * N_ + i] != 0);
    }
    __syncthreads();

    // prologue: issue rows 0..7 into ring slots 0..7 (2 loads each)
    #pragma unroll
    for (int r = 0; r < 8; ++r) {
        uint32_t base = rps[r];
        ld_lds_64u32(pk + base,      &ring[r * 128]);
        ld_lds_64u32(pk + base + 64, &ring[r * 128 + 64]);
    }
    asm volatile("s_waitcnt vmcnt(14)" ::: "memory");   // row 0's slot complete
    uint32_t pkA0 = ring[lane];
    uint32_t pkA1 = ring[64 + lane];
    uint4 mcur = *(const uint4*)&rm4[0];
    uint8_t mkc = mk[0], mkn = mk[1];
    uint32_t rpI = rps[8];                              // base for row 8 issue
    unsigned long long below = (1ULL << lane) - 1ULL;

    for (int n = 0; n < N_; ++n) {
        // A. issue prefetch for row n+8 (exactly 2 loads per iter keeps vmcnt math exact)
        uint32_t slotW = (uint32_t)((n + 8) & 15);
        ld_lds_64u32(pk + rpI,      &ring[slotW * 128]);
        ld_lds_64u32(pk + rpI + 64, &ring[slotW * 128 + 64]);
        // B. next issue base (row n+9), off-chain LDS read
        int r9 = n + 9; if (r9 > N_ - 1) r9 = N_ - 1;
        uint32_t rpI_next = rps[r9];

        // C. process row n from registers
        uint32_t w01 = (lane < 32) ? mcur.x : mcur.y;
        uint32_t w23 = (lane < 32) ? mcur.z : mcur.w;
        uint32_t a0 = (w01 >> (lane & 31)) & 1u;
        uint32_t a1 = (w23 >> (lane & 31)) & 1u;
        unsigned long long b0 = __ballot(a0 != 0), b1 = __ballot(a1 != 0);
        uint32_t num = (uint32_t)__popcll(b0) + (uint32_t)__popcll(b1);
        if (mkc && num > 1u) {
            bool allrm = num <= (uint32_t)TDIL;         // sf==1 -> remove all
            uint32_t sf = (num + 1u) >> 1;              // ceil(num/2)
            uint32_t r2 = (num & 1u) ? 0xFFFFFFFFu : num;
            uint32_t rank0 = (uint32_t)__popcll(b0 & below) + 1u;
            uint32_t rank1 = (uint32_t)__popcll(b0) + (uint32_t)__popcll(b1 & below) + 1u;
            bool rm0 = a0 && (allrm || rank0 == sf || rank0 == r2);
            bool rm1 = a1 && (allrm || rank1 == sf || rank1 == r2);
            unsigned long long rb0 = __ballot(rm0), rb1 = __ballot(rm1);
            if (rm0) {
                uint32_t c = pkA0 & 0xFFFFu, ml = pkA0 >> 16;
                if (ml < 128u) atomicAnd(&rm4[c * 4 + (ml >> 5)], ~(1u << (ml & 31)));
            }
            if (rm1) {
                uint32_t c = pkA1 & 0xFFFFu, ml = pkA1 >> 16;
                if (ml < 128u) atomicAnd(&rm4[c * 4 + (ml >> 5)], ~(1u << (ml & 31)));
            }
            if (lane == 0) {
                uint4 nm;
                nm.x = mcur.x & ~(uint32_t)rb0;
                nm.y = mcur.y & ~(uint32_t)(rb0 >> 32);
                nm.z = mcur.z & ~(uint32_t)rb1;
                nm.w = mcur.w & ~(uint32_t)(rb1 >> 32);
                *(uint4*)&rm4[(size_t)n * 4] = nm;
            }
        }

        // D. counted wait: row n+1's 2 loads complete (14 newer loads may stay in flight)
        asm volatile("s_waitcnt vmcnt(14)" ::: "memory");
        uint32_t slotR = (uint32_t)((n + 1) & 15);
        pkA0 = ring[slotR * 128 + lane];
        pkA1 = ring[slotR * 128 + 64 + lane];
        // read next row's mask AFTER this row's atomics (in-order DS per wave)
        if (n + 1 < N_) mcur = *(const uint4*)&rm4[(size_t)(n + 1) * 4];
        mkc = mkn;
        int r2i = n + 2; if (r2i > N_ - 1) r2i = N_ - 1;
        mkn = mk[r2i];
        rpI = rpI_next;
    }
    __syncthreads();
    for (int i = lane; i < N_; i += 64) {
        uint4 mm = *(const uint4*)&rm4[(size_t)i * 4];
        *(uint4*)&rmaskg[((size_t)b * N_ + i) * 4] = mm;
        degf[b * N_ + i] = (uint32_t)(__popc(mm.x) + __popc(mm.y) + __popc(mm.z) + __popc(mm.w));
    }
}

// ---------------- K6: compact surviving cols in place (from rank masks) ----------------
__global__ __launch_bounds__(256) void k6_compact(uint16_t* __restrict__ cols,
        const uint32_t* __restrict__ rowptr, const uint32_t* __restrict__ rmaskg) {
    int row  = blockIdx.x * 4 + (threadIdx.x >> 6);
    int lane = threadIdx.x & 63;
    int b = row >> 11, n = row & (N_ - 1);
    uint16_t* cb = cols + (size_t)b * EMAX;
    uint4 mm = *(const uint4*)&rmaskg[(size_t)row * 4];
    uint32_t st = rowptr[(size_t)b * RPS + n];
    uint32_t w01 = (lane < 32) ? mm.x : mm.y;
    uint32_t w23 = (lane < 32) ? mm.z : mm.w;
    uint32_t a0 = (w01 >> (lane & 31)) & 1u;
    uint32_t a1 = (w23 >> (lane & 31)) & 1u;
    unsigned long long b0 = __ballot(a0 != 0), b1 = __ballot(a1 != 0);
    unsigned long long below = (1ULL << lane) - 1ULL;
    uint16_t c0v = 0, c1v = 0;
    if (a0) c0v = cb[st + lane];
    if (a1) c1v = cb[st + 64 + lane];
    uint32_t i0 = st + (uint32_t)__popcll(b0 & below);
    uint32_t i1 = st + (uint32_t)__popcll(b0) + (uint32_t)__popcll(b1 & below);
    if (a0) cb[i0] = c0v;
    if (a1) cb[i1] = c1v;
}

// ---------------- K7: SpMM mean-aggregate (1 wave per row) ----------------
__global__ __launch_bounds__(256) void k7_spmm(const float* __restrict__ X,
        const uint16_t* __restrict__ cols, const uint32_t* __restrict__ rowptr,
        const uint32_t* __restrict__ degf, float* __restrict__ agg) {
    int wid  = blockIdx.x * 4 + (threadIdx.x >> 6);
    int lane = threadIdx.x & 63;
    int b = wid >> 11, n = wid & (N_ - 1);
    const uint16_t* cb = cols + (size_t)b * EMAX;
    uint32_t start = rowptr[(size_t)b * RPS + n];
    uint32_t cnt = degf[wid];
    const float* Xb = X + ((size_t)b * N_) * D_;
    float ax = 0.f, ay = 0.f;
    for (uint32_t base = 0; base < cnt; base += 64) {
        int idx = (int)base + lane;
        int cl = (idx < (int)cnt) ? (int)cb[start + idx] : 0;
        int kmax = (int)cnt - (int)base; if (kmax > 64) kmax = 64;
        for (int k = 0; k < kmax; ++k) {
            int c = __shfl(cl, k);
            float2 v = ((const float2*)(Xb + (size_t)c * D_))[lane];
            ax += v.x; ay += v.y;
        }
    }
    float inv = 1.0f / (float)(cnt ? cnt : 1u);
    ((float2*)(agg + (size_t)wid * D_))[lane] = make_float2(ax * inv, ay * inv);
}

// ---------------- K8: sage GEMM + bias + L2norm + mask + relu + BN partials ----------------
__global__ __launch_bounds__(256) void k8_gemm(const float* __restrict__ agg,
        const float* __restrict__ X, const float* __restrict__ Wr,
        const float* __restrict__ Wx, const float* __restrict__ bias,
        const int* __restrict__ mask, float* __restrict__ P,
        float* __restrict__ bnstat) {
    __shared__ float aL[32 * 128];
    __shared__ float xL[32 * 128];
    int tid = threadIdx.x;
    size_t row0 = (size_t)blockIdx.x * 32;
    for (int t = tid * 4; t < 32 * 128; t += 1024) {
        *(float4*)&aL[t] = *(const float4*)&agg[row0 * 128 + t];
        *(float4*)&xL[t] = *(const float4*)&X[row0 * 128 + t];
    }
    __syncthreads();
    int h = tid >> 6;
    int c0 = (tid & 63) * 2;
    float2 acc[8];
    #pragma unroll
    for (int i = 0; i < 8; ++i) acc[i] = make_float2(0.f, 0.f);
    for (int k4 = 0; k4 < 128; k4 += 4) {
        float2 wr[4], wx[4];
        #pragma unroll
        for (int kk = 0; kk < 4; ++kk) {
            wr[kk] = *(const float2*)&Wr[(k4 + kk) * 128 + c0];
            wx[kk] = *(const float2*)&Wx[(k4 + kk) * 128 + c0];
        }
        #pragma unroll
        for (int i = 0; i < 8; ++i) {
            int r = h * 8 + i;
            float4 a4 = *(const float4*)&aL[r * 128 + k4];
            float4 x4 = *(const float4*)&xL[r * 128 + k4];
            acc[i].x += a4.x * wr[0].x + a4.y * wr[1].x + a4.z * wr[2].x + a4.w * wr[3].x
                      + x4.x * wx[0].x + x4.y * wx[1].x + x4.z * wx[2].x + x4.w * wx[3].x;
            acc[i].y += a4.x * wr[0].y + a4.y * wr[1].y + a4.z * wr[2].y + a4.w * wr[3].y
                      + x4.x * wx[0].y + x4.y * wx[1].y + x4.z * wx[2].y + x4.w * wx[3].y;
        }
    }
    float b0 = bias[c0], b1v = bias[c0 + 1];
    __syncthreads();
    #pragma unroll
    for (int i = 0; i < 8; ++i) {
        int r = h * 8 + i;
        aL[r * 128 + c0]     = acc[i].x + b0;
        aL[r * 128 + c0 + 1] = acc[i].y + b1v;
    }
    __syncthreads();
    int lane = tid & 63;
    #pragma unroll
    for (int i = 0; i < 8; ++i) {
        int r = h * 8 + i;
        float v0 = aL[r * 128 + lane], v1 = aL[r * 128 + lane + 64];
        float s = v0 * v0 + v1 * v1;
        #pragma unroll
        for (int off = 32; off >= 1; off >>= 1) s += __shfl_xor(s, off);
        float nrm = fmaxf(sqrtf(s), 1e-12f);
        float mf = (mask[row0 + r] != 0) ? 1.f : 0.f;
        float inv = mf / nrm;
        float p0 = fmaxf(v0 * inv, 0.f), p1 = fmaxf(v1 * inv, 0.f);
        P[(row0 + r) * 128 + lane]      = p0;
        P[(row0 + r) * 128 + lane + 64] = p1;
        aL[r * 128 + lane] = p0; aL[r * 128 + lane + 64] = p1;
    }
    __syncthreads();
    if (tid < 128) {
        float s = 0.f, q = 0.f;
        #pragma unroll
        for (int r = 0; r < 32; ++r) { float v = aL[r * 128 + tid]; s += v; q += v * v; }
        atomicAdd(&bnstat[tid], s);
        atomicAdd(&bnstat[128 + tid], q);
    }
}

// ---------------- K10: BatchNorm apply (training stats, biased var), in place ----------------
__global__ __launch_bounds__(256) void k10_bn(float* __restrict__ P,
        const float* __restrict__ bn, const float* __restrict__ g,
        const float* __restrict__ be) {
    int c = threadIdx.x & 127;
    int half = threadIdx.x >> 7;
    size_t base = (size_t)blockIdx.x * 16;
    float mean = bn[c] * (1.f / 16384.f);
    float var  = bn[128 + c] * (1.f / 16384.f) - mean * mean;
    float sc = g[c] * rsqrtf(var + 1e-5f);
    float sh = be[c] - mean * sc;
    for (int r = half; r < 16; r += 2) {
        size_t i = (base + r) * 128 + c;
        P[i] = P[i] * sc + sh;
    }
}

// ---------------- K11: final (concat * mf) @ Wl + bl, * mf ----------------
__global__ __launch_bounds__(256) void k11_final(const float* __restrict__ h1,
        const float* __restrict__ h2, const float* __restrict__ h3,
        const float* __restrict__ Wl, const float* __restrict__ bl,
        const int* __restrict__ mask, float* __restrict__ out) {
    __shared__ float s1[32 * 128], s2[32 * 128], s3[32 * 128];
    int tid = threadIdx.x;
    size_t row0 = (size_t)blockIdx.x * 32;
    for (int t = tid * 4; t < 32 * 128; t += 1024) {
        int r = t >> 7;
        float mf = (mask[row0 + r] != 0) ? 1.f : 0.f;
        float4 a = *(const float4*)&h1[row0 * 128 + t];
        float4 b = *(const float4*)&h2[row0 * 128 + t];
        float4 c = *(const float4*)&h3[row0 * 128 + t];
        a.x *= mf; a.y *= mf; a.z *= mf; a.w *= mf;
        b.x *= mf; b.y *= mf; b.z *= mf; b.w *= mf;
        c.x *= mf; c.y *= mf; c.z *= mf; c.w *= mf;
        *(float4*)&s1[t] = a; *(float4*)&s2[t] = b; *(float4*)&s3[t] = c;
    }
    __syncthreads();
    int h = tid >> 6, c0 = (tid & 63) * 2;
    float2 acc[8];
    #pragma unroll
    for (int i = 0; i < 8; ++i) acc[i] = make_float2(0.f, 0.f);
    for (int k4 = 0; k4 < 128; k4 += 4) {
        float2 w1[4], w2[4], w3[4];
        #pragma unroll
        for (int kk = 0; kk < 4; ++kk) {
            w1[kk] = *(const float2*)&Wl[(k4 + kk) * 128 + c0];
            w2[kk] = *(const float2*)&Wl[(128 + k4 + kk) * 128 + c0];
            w3[kk] = *(const float2*)&Wl[(256 + k4 + kk) * 128 + c0];
        }
        #pragma unroll
        for (int i = 0; i < 8; ++i) {
            int r = h * 8 + i;
            float4 a = *(const float4*)&s1[r * 128 + k4];
            float4 b = *(const float4*)&s2[r * 128 + k4];
            float4 c = *(const float4*)&s3[r * 128 + k4];
            acc[i].x += a.x * w1[0].x + a.y * w1[1].x + a.z * w1[2].x + a.w * w1[3].x
                      + b.x * w2[0].x + b.y * w2[1].x + b.z * w2[2].x + b.w * w2[3].x
                      + c.x * w3[0].x + c.y * w3[1].x + c.z * w3[2].x + c.w * w3[3].x;
            acc[i].y += a.x * w1[0].y + a.y * w1[1].y + a.z * w1[2].y + a.w * w1[3].y
                      + b.x * w2[0].y + b.y * w2[1].y + b.z * w2[2].y + b.w * w2[3].y
                      + c.x * w3[0].y + c.y * w3[1].y + c.z * w3[2].y + c.w * w3[3].y;
        }
    }
    float bx = bl[c0], by = bl[c0 + 1];
    #pragma unroll
    for (int i = 0; i < 8; ++i) {
        int r = h * 8 + i;
        float mf = (mask[row0 + r] != 0) ? 1.f : 0.f;
        *(float2*)&out[(row0 + r) * 128 + c0] =
            make_float2((acc[i].x + bx) * mf, (acc[i].y + by) * mf);
    }
}

// ---------------- launch ----------------
extern "C" void kernel_launch(void* const* d_in, const int* in_sizes, int n_in,
                              void* d_out, int out_size, void* d_ws, size_t ws_size,
                              hipStream_t stream) {
    (void)in_sizes; (void)n_in; (void)out_size; (void)ws_size;
    const float* x    = (const float*)d_in[0];
    const float* adj  = (const float*)d_in[1];
    const int*   mask = (const int*)d_in[2];
    const float* Wr1 = (const float*)d_in[3],  *Wx1 = (const float*)d_in[4];
    const float* b1  = (const float*)d_in[5],  *g1  = (const float*)d_in[6],  *be1 = (const float*)d_in[7];
    const float* Wr2 = (const float*)d_in[8],  *Wx2 = (const float*)d_in[9];
    const float* b2  = (const float*)d_in[10], *g2  = (const float*)d_in[11], *be2 = (const float*)d_in[12];
    const float* Wr3 = (const float*)d_in[13], *Wx3 = (const float*)d_in[14];
    const float* b3  = (const float*)d_in[15], *g3  = (const float*)d_in[16], *be3 = (const float*)d_in[17];
    const float* Wl  = (const float*)d_in[18], *bl  = (const float*)d_in[19];

    char* ws = (char*)d_ws;
    uint32_t* bitset = (uint32_t*)(ws + OFF_BITSET);
    float*    agg    = (float*)(ws + OFF_AGG);
    float*    h1     = (float*)(ws + OFF_H1);
    float*    h2     = (float*)(ws + OFF_H2);
    float*    h3     = (float*)(ws + OFF_H3);
    uint16_t* cols   = (uint16_t*)(ws + OFF_COLS);
    uint32_t* packed = (uint32_t*)(ws + OFF_PACKED);
    uint32_t* rp     = (uint32_t*)(ws + OFF_RP);
    uint32_t* deg0   = (uint32_t*)(ws + OFF_DEG0);
    uint32_t* degf   = (uint32_t*)(ws + OFF_DEGF);
    uint32_t* rmaskg = (uint32_t*)(ws + OFF_RMASK);
    float*    bn     = (float*)(ws + OFF_BN);
    float*    out    = (float*)d_out;

    k0_zero   <<<1,    256, 0, stream>>>(bn);
    k1_bitset <<<4096, 256, 0, stream>>>(adj, bitset, deg0);
    k2_rowptr <<<8,    256, 0, stream>>>(deg0, rp);
    k3_cols   <<<4096, 256, 0, stream>>>(bitset, rp, cols);
    k4_packed <<<4096, 256, 0, stream>>>(cols, rp, packed);
    k5_dilate <<<8,    64,  0, stream>>>(packed, rp, deg0, mask, rmaskg, degf);
    k6_compact<<<4096, 256, 0, stream>>>(cols, rp, rmaskg);
    // layer 1
    k7_spmm   <<<4096, 256, 0, stream>>>(x,  cols, rp, degf, agg);
    k8_gemm   <<<512,  256, 0, stream>>>(agg, x,  Wr1, Wx1, b1, mask, h1, bn + 0);
    k10_bn    <<<1024, 256, 0, stream>>>(h1, bn + 0,   g1, be1);
    // layer 2
    k7_spmm   <<<4096, 256, 0, stream>>>(h1, cols, rp, degf, agg);
    k8_gemm   <<<512,  256, 0, stream>>>(agg, h1, Wr2, Wx2, b2, mask, h2, bn + 256);
    k10_bn    <<<1024, 256, 0, stream>>>(h2, bn + 256, g2, be2);
    // layer 3
    k7_spmm   <<<4096, 256, 0, stream>>>(h2, cols, rp, degf, agg);
    k8_gemm   <<<512,  256, 0, stream>>>(agg, h2, Wr3, Wx3, b3, mask, h3, bn + 512);
    k10_bn    <<<1024, 256, 0, stream>>>(h3, bn + 512, g3, be3);
    // final
    k11_final <<<512,  256, 0, stream>>>(h1, h2, h3, Wl, bl, mask, out);
}

// Round 4
// 960.083 us; speedup vs baseline: 1.2274x; 1.0872x over previous
//
#include <hip/hip_runtime.h>
#include <cstdint>

// ---------------- problem constants ----------------
constexpr int B_ = 8, N_ = 2048, D_ = 128, NW = 64;   // NW = words per bitset row
constexpr int EMAX = 131072;                           // per-batch edge capacity
constexpr int RPS = 2064;                              // rowptr stride per batch
constexpr int TDIL = 10;

// ---------------- workspace layout (bytes) ----------------
constexpr size_t OFF_BITSET = 0;                  // 4MB (preproc), reused as agg (8MB)
constexpr size_t OFF_AGG    = 0;
constexpr size_t OFF_H1     = (size_t)8  << 20;
constexpr size_t OFF_H2     = (size_t)16 << 20;
constexpr size_t OFF_H3     = (size_t)24 << 20;
constexpr size_t OFF_COLS   = (size_t)32 << 20;   // u16 [B][EMAX]  (2MB)
constexpr size_t OFF_PACKED = (size_t)34 << 20;   // u32 [B][EMAX]  (4MB): col | mlocal<<16
constexpr size_t OFF_RP     = (size_t)38 << 20;   // u32 [B][RPS]
constexpr size_t OFF_DEG0   = OFF_RP   + ((size_t)128 << 10);
constexpr size_t OFF_DEGF   = OFF_DEG0 + ((size_t)64  << 10);
constexpr size_t OFF_RMASK  = OFF_DEGF + ((size_t)64  << 10);  // u32 [B][N][4] (256KB)
constexpr size_t OFF_BN     = OFF_RMASK + ((size_t)256 << 10); // 3*256 floats

// ---------------- K0: zero BN stats ----------------
__global__ void k0_zero(float* bn) {
    for (int i = threadIdx.x; i < 768; i += 256) bn[i] = 0.f;
}

// ---------------- K1: adj (fp32 0/1) -> bitset + degrees ----------------
__global__ __launch_bounds__(256) void k1_bitset(const float* __restrict__ adj,
        uint32_t* __restrict__ bitset, uint32_t* __restrict__ deg0) {
    int row  = blockIdx.x * 4 + (threadIdx.x >> 6);
    int lane = threadIdx.x & 63;
    const float* ar = adj + (size_t)row * N_;
    uint32_t myw = 0;
    #pragma unroll 4
    for (int it = 0; it < 32; ++it) {
        float v = ar[it * 64 + lane];
        unsigned long long m = __ballot(v != 0.0f);
        if (lane == 2 * it)          myw = (uint32_t)m;
        else if (lane == 2 * it + 1) myw = (uint32_t)(m >> 32);
    }
    bitset[(size_t)row * NW + lane] = myw;
    int pc = __popc(myw);
    #pragma unroll
    for (int off = 32; off >= 1; off >>= 1) pc += __shfl_xor(pc, off);
    if (lane == 0) deg0[row] = (uint32_t)pc;
}

// ---------------- K2: per-batch prefix sum of degrees -> rowptr ----------------
__global__ __launch_bounds__(256) void k2_rowptr(const uint32_t* __restrict__ deg0,
        uint32_t* __restrict__ rowptr) {
    int b = blockIdx.x, t = threadIdx.x;
    __shared__ uint32_t tsum[256];
    uint32_t v[8]; uint32_t s = 0;
    #pragma unroll
    for (int j = 0; j < 8; ++j) { v[j] = deg0[b * N_ + t * 8 + j]; s += v[j]; v[j] = s; }
    tsum[t] = s;
    __syncthreads();
    for (int off = 1; off < 256; off <<= 1) {
        uint32_t xv = (t >= off) ? tsum[t - off] : 0u;
        __syncthreads();
        tsum[t] += xv;
        __syncthreads();
    }
    uint32_t excl = tsum[t] - s;
    uint32_t* rp = rowptr + (size_t)b * RPS;
    if (t == 0) rp[0] = 0;
    #pragma unroll
    for (int j = 0; j < 8; ++j) {
        uint32_t val = excl + v[j];
        if (val > (uint32_t)EMAX) val = EMAX;   // safety clamp
        rp[t * 8 + j + 1] = val;
    }
}

// ---------------- K3: fill sorted column lists ----------------
__global__ __launch_bounds__(256) void k3_cols(const uint32_t* __restrict__ bitset,
        const uint32_t* __restrict__ rowptr, uint16_t* __restrict__ cols) {
    int row  = blockIdx.x * 4 + (threadIdx.x >> 6);
    int lane = threadIdx.x & 63;
    int b = row >> 11, n = row & (N_ - 1);
    uint32_t w = bitset[(size_t)row * NW + lane];
    uint32_t pc = __popc(w);
    uint32_t inc = pc;
    #pragma unroll
    for (int off = 1; off < 64; off <<= 1) {
        uint32_t t = __shfl_up(inc, off);
        if (lane >= off) inc += t;
    }
    uint32_t base = rowptr[(size_t)b * RPS + n] + (inc - pc);
    uint16_t* cb = cols + (size_t)b * EMAX;
    while (w) {
        int bit = __builtin_ctz(w); w &= w - 1;
        if (base < (uint32_t)EMAX) cb[base] = (uint16_t)(lane * 32 + bit);
        ++base;
    }
}

// ---------------- K4: packed (col | mate_local<<16) via binary search ----------------
__global__ __launch_bounds__(256) void k4_packed(const uint16_t* __restrict__ cols,
        const uint32_t* __restrict__ rowptr, uint32_t* __restrict__ packed) {
    int row  = blockIdx.x * 4 + (threadIdx.x >> 6);
    int lane = threadIdx.x & 63;
    int b = row >> 11, n = row & (N_ - 1);
    const uint32_t* rpb = rowptr + (size_t)b * RPS;
    const uint16_t* cb  = cols + (size_t)b * EMAX;
    uint32_t start = rpb[n], end = rpb[n + 1];
    for (uint32_t e = start + lane; e < end; e += 64) {
        uint32_t j = cb[e];
        uint32_t lo = rpb[j], hi = rpb[j + 1];
        uint32_t rj = lo;
        while (lo < hi) {
            uint32_t mid = (lo + hi) >> 1;
            if ((int)cb[mid] < n) lo = mid + 1; else hi = mid;
        }
        packed[(size_t)b * EMAX + e] = j | ((lo - rj) << 16);
    }
}

// ---------------- K5: sequential dilation, producer/consumer (2 waves/batch) ----------
// Consumer wave executes ZERO VMEM ops: its vmcnt is always 0, so any
// compiler-inserted vmcnt waits are free. Producer wave streams packed rows
// (128 u32 each) into a 64-slot LDS ring with double-buffered VGPR group loads.
// Sync: ready (producer->consumer, release/acquire), done (consumer->producer).
__global__ __launch_bounds__(128) void k5_dilate(
        const uint32_t* __restrict__ packed, const uint32_t* __restrict__ rowptr,
        const uint32_t* __restrict__ deg0, const int* __restrict__ mask,
        uint32_t* __restrict__ rmaskg, uint32_t* __restrict__ degf) {
    int b = blockIdx.x;
    int tid = threadIdx.x;
    int lane = tid & 63;
    int wv = tid >> 6;
    __shared__ __align__(16) uint32_t rm4[N_ * 4];    // 32KB
    __shared__ uint32_t rps[N_ + 1];                  // 8.2KB
    __shared__ uint8_t  mk[N_];                       // 2KB
    __shared__ __align__(16) uint32_t ring[64 * 128]; // 32KB: 64 row slots
    __shared__ uint32_t ready_c, done_c;
    const uint32_t* pk  = packed + (size_t)b * EMAX;
    const uint32_t* rpg = rowptr + (size_t)b * RPS;

    for (int i = tid; i <= N_; i += 128) rps[i] = rpg[i];
    for (int i = tid; i < N_; i += 128) {
        int d = (int)deg0[b * N_ + i]; if (d > 128) d = 128;
        uint4 mm;
        mm.x = (d >= 32) ? ~0u : ((d > 0)  ? ((1u << d)        - 1u) : 0u);
        mm.y = (d >= 64) ? ~0u : ((d > 32) ? ((1u << (d - 32)) - 1u) : 0u);
        mm.z = (d >= 96) ? ~0u : ((d > 64) ? ((1u << (d - 64)) - 1u) : 0u);
        mm.w = (d >= 128)? ~0u : ((d > 96) ? ((1u << (d - 96)) - 1u) : 0u);
        *(uint4*)&rm4[(size_t)i * 4] = mm;
        mk[i] = (uint8_t)(mask[b * N_ + i] != 0);
    }
    if (tid == 0) { ready_c = 0u; done_c = 0u; }
    __syncthreads();

    if (wv == 1) {
        // ================= PRODUCER =================
        const int NG = N_ / 8;                         // 256 groups of 8 rows
        uint32_t A0[8], A1[8], B0[8], B1[8];
        #pragma unroll
        for (int r = 0; r < 8; ++r) {                  // issue group 0 -> A
            uint32_t base = rps[r];
            A0[r] = pk[base + lane]; A1[r] = pk[base + 64 + lane];
        }
        #pragma unroll
        for (int r = 0; r < 8; ++r) {                  // issue group 1 -> B
            uint32_t base = rps[8 + r];
            B0[r] = pk[base + lane]; B1[r] = pk[base + 64 + lane];
        }
        for (int g = 0; g < NG; g += 2) {
            // ---- write group g (A); its loads were issued a full loop ago ----
            int need = 8 * g + 8 - 64;
            if (need > 0)
                while ((int)__hip_atomic_load(&done_c, __ATOMIC_ACQUIRE,
                        __HIP_MEMORY_SCOPE_WORKGROUP) < need) {}
            #pragma unroll
            for (int r = 0; r < 8; ++r) {
                uint32_t slot = (uint32_t)((g * 8 + r) & 63) * 128;
                ring[slot + lane] = A0[r];
                ring[slot + 64 + lane] = A1[r];
            }
            if (lane == 0)
                __hip_atomic_store(&ready_c, (uint32_t)(8 * g + 8),
                        __ATOMIC_RELEASE, __HIP_MEMORY_SCOPE_WORKGROUP);
            if (g + 2 < NG) {                          // issue group g+2 -> A
                #pragma unroll
                for (int r = 0; r < 8; ++r) {
                    uint32_t base = rps[(g + 2) * 8 + r];
                    A0[r] = pk[base + lane]; A1[r] = pk[base + 64 + lane];
                }
            }
            // ---- write group g+1 (B) ----
            need = 8 * (g + 1) + 8 - 64;
            if (need > 0)
                while ((int)__hip_atomic_load(&done_c, __ATOMIC_ACQUIRE,
                        __HIP_MEMORY_SCOPE_WORKGROUP) < need) {}
            #pragma unroll
            for (int r = 0; r < 8; ++r) {
                uint32_t slot = (uint32_t)(((g + 1) * 8 + r) & 63) * 128;
                ring[slot + lane] = B0[r];
                ring[slot + 64 + lane] = B1[r];
            }
            if (lane == 0)
                __hip_atomic_store(&ready_c, (uint32_t)(8 * (g + 1) + 8),
                        __ATOMIC_RELEASE, __HIP_MEMORY_SCOPE_WORKGROUP);
            if (g + 3 < NG) {                          // issue group g+3 -> B
                #pragma unroll
                for (int r = 0; r < 8; ++r) {
                    uint32_t base = rps[(g + 3) * 8 + r];
                    B0[r] = pk[base + lane]; B1[r] = pk[base + 64 + lane];
                }
            }
        }
    } else {
        // ================= CONSUMER (no VMEM ops) =================
        unsigned long long below = (1ULL << lane) - 1ULL;
        while (__hip_atomic_load(&ready_c, __ATOMIC_ACQUIRE,
                __HIP_MEMORY_SCOPE_WORKGROUP) < 16u) {}
        uint32_t pkA0 = ring[lane],        pkA1 = ring[64 + lane];
        uint32_t pkB0 = ring[128 + lane],  pkB1 = ring[128 + 64 + lane];
        uint4 mcur = *(const uint4*)&rm4[0];
        uint8_t mkc = mk[0], mkn = mk[1];
        for (int n = 0; n < N_; ++n) {
            if ((n & 7) == 0 && n) {
                if (lane == 0)
                    __hip_atomic_store(&done_c, (uint32_t)n,
                            __ATOMIC_RELEASE, __HIP_MEMORY_SCOPE_WORKGROUP);
                uint32_t want = (uint32_t)((n + 16 > N_) ? N_ : n + 16);
                while (__hip_atomic_load(&ready_c, __ATOMIC_ACQUIRE,
                        __HIP_MEMORY_SCOPE_WORKGROUP) < want) {}
            }
            // prefetch packed for row n+2 (static data, off the dependency chain)
            int rn = n + 2; if (rn >= N_) rn = N_ - 1;
            uint32_t slot = (uint32_t)(rn & 63) * 128;
            uint32_t pkN0 = ring[slot + lane], pkN1 = ring[slot + 64 + lane];

            // process row n
            uint32_t w01 = (lane < 32) ? mcur.x : mcur.y;
            uint32_t w23 = (lane < 32) ? mcur.z : mcur.w;
            uint32_t a0 = (w01 >> (lane & 31)) & 1u;
            uint32_t a1 = (w23 >> (lane & 31)) & 1u;
            unsigned long long bl0 = __ballot(a0 != 0), bl1 = __ballot(a1 != 0);
            uint32_t num = (uint32_t)__popcll(bl0) + (uint32_t)__popcll(bl1);
            if (mkc && num > 1u) {
                bool allrm = num <= (uint32_t)TDIL;     // sf==1 -> remove all
                uint32_t sf = (num + 1u) >> 1;          // ceil(num/2)
                uint32_t r2 = (num & 1u) ? 0xFFFFFFFFu : num;
                uint32_t rank0 = (uint32_t)__popcll(bl0 & below) + 1u;
                uint32_t rank1 = (uint32_t)__popcll(bl0) + (uint32_t)__popcll(bl1 & below) + 1u;
                bool rm0 = a0 && (allrm || rank0 == sf || rank0 == r2);
                bool rm1 = a1 && (allrm || rank1 == sf || rank1 == r2);
                unsigned long long rb0 = __ballot(rm0), rb1 = __ballot(rm1);
                if (rm0) {
                    uint32_t c = pkA0 & 0xFFFFu, ml = pkA0 >> 16;
                    if (ml < 128u) atomicAnd(&rm4[c * 4 + (ml >> 5)], ~(1u << (ml & 31)));
                }
                if (rm1) {
                    uint32_t c = pkA1 & 0xFFFFu, ml = pkA1 >> 16;
                    if (ml < 128u) atomicAnd(&rm4[c * 4 + (ml >> 5)], ~(1u << (ml & 31)));
                }
                if (lane == 0) {
                    uint4 nm;
                    nm.x = mcur.x & ~(uint32_t)rb0;
                    nm.y = mcur.y & ~(uint32_t)(rb0 >> 32);
                    nm.z = mcur.z & ~(uint32_t)rb1;
                    nm.w = mcur.w & ~(uint32_t)(rb1 >> 32);
                    *(uint4*)&rm4[(size_t)n * 4] = nm;
                }
            }
            // next row's mask: issued after atomics; per-wave in-order DS completion
            if (n + 1 < N_) mcur = *(const uint4*)&rm4[(size_t)(n + 1) * 4];
            mkc = mkn;
            int r2i = n + 2; if (r2i > N_ - 1) r2i = N_ - 1;
            mkn = mk[r2i];
            pkA0 = pkB0; pkA1 = pkB1; pkB0 = pkN0; pkB1 = pkN1;
        }
        if (lane == 0)
            __hip_atomic_store(&done_c, (uint32_t)N_,
                    __ATOMIC_RELEASE, __HIP_MEMORY_SCOPE_WORKGROUP);
    }
    __syncthreads();
    for (int i = tid; i < N_; i += 128) {
        uint4 mm = *(const uint4*)&rm4[(size_t)i * 4];
        *(uint4*)&rmaskg[((size_t)b * N_ + i) * 4] = mm;
        degf[b * N_ + i] = (uint32_t)(__popc(mm.x) + __popc(mm.y) + __popc(mm.z) + __popc(mm.w));
    }
}

// ---------------- K6: compact surviving cols in place (from rank masks) ----------------
__global__ __launch_bounds__(256) void k6_compact(uint16_t* __restrict__ cols,
        const uint32_t* __restrict__ rowptr, const uint32_t* __restrict__ rmaskg) {
    int row  = blockIdx.x * 4 + (threadIdx.x >> 6);
    int lane = threadIdx.x & 63;
    int b = row >> 11, n = row & (N_ - 1);
    uint16_t* cb = cols + (size_t)b * EMAX;
    uint4 mm = *(const uint4*)&rmaskg[(size_t)row * 4];
    uint32_t st = rowptr[(size_t)b * RPS + n];
    uint32_t w01 = (lane < 32) ? mm.x : mm.y;
    uint32_t w23 = (lane < 32) ? mm.z : mm.w;
    uint32_t a0 = (w01 >> (lane & 31)) & 1u;
    uint32_t a1 = (w23 >> (lane & 31)) & 1u;
    unsigned long long b0 = __ballot(a0 != 0), b1 = __ballot(a1 != 0);
    unsigned long long below = (1ULL << lane) - 1ULL;
    uint16_t c0v = 0, c1v = 0;
    if (a0) c0v = cb[st + lane];
    if (a1) c1v = cb[st + 64 + lane];
    uint32_t i0 = st + (uint32_t)__popcll(b0 & below);
    uint32_t i1 = st + (uint32_t)__popcll(b0) + (uint32_t)__popcll(b1 & below);
    if (a0) cb[i0] = c0v;
    if (a1) cb[i1] = c1v;
}

// ---------------- K7: SpMM mean-aggregate (1 wave per row) ----------------
__global__ __launch_bounds__(256) void k7_spmm(const float* __restrict__ X,
        const uint16_t* __restrict__ cols, const uint32_t* __restrict__ rowptr,
        const uint32_t* __restrict__ degf, float* __restrict__ agg) {
    int wid  = blockIdx.x * 4 + (threadIdx.x >> 6);
    int lane = threadIdx.x & 63;
    int b = wid >> 11, n = wid & (N_ - 1);
    const uint16_t* cb = cols + (size_t)b * EMAX;
    uint32_t start = rowptr[(size_t)b * RPS + n];
    uint32_t cnt = degf[wid];
    const float* Xb = X + ((size_t)b * N_) * D_;
    float ax = 0.f, ay = 0.f;
    for (uint32_t base = 0; base < cnt; base += 64) {
        int idx = (int)base + lane;
        int cl = (idx < (int)cnt) ? (int)cb[start + idx] : 0;
        int kmax = (int)cnt - (int)base; if (kmax > 64) kmax = 64;
        for (int k = 0; k < kmax; ++k) {
            int c = __shfl(cl, k);
            float2 v = ((const float2*)(Xb + (size_t)c * D_))[lane];
            ax += v.x; ay += v.y;
        }
    }
    float inv = 1.0f / (float)(cnt ? cnt : 1u);
    ((float2*)(agg + (size_t)wid * D_))[lane] = make_float2(ax * inv, ay * inv);
}

// ---------------- K8: sage GEMM + bias + L2norm + mask + relu + BN partials ----------------
__global__ __launch_bounds__(256) void k8_gemm(const float* __restrict__ agg,
        const float* __restrict__ X, const float* __restrict__ Wr,
        const float* __restrict__ Wx, const float* __restrict__ bias,
        const int* __restrict__ mask, float* __restrict__ P,
        float* __restrict__ bnstat) {
    __shared__ float aL[32 * 128];
    __shared__ float xL[32 * 128];
    int tid = threadIdx.x;
    size_t row0 = (size_t)blockIdx.x * 32;
    for (int t = tid * 4; t < 32 * 128; t += 1024) {
        *(float4*)&aL[t] = *(const float4*)&agg[row0 * 128 + t];
        *(float4*)&xL[t] = *(const float4*)&X[row0 * 128 + t];
    }
    __syncthreads();
    int h = tid >> 6;
    int c0 = (tid & 63) * 2;
    float2 acc[8];
    #pragma unroll
    for (int i = 0; i < 8; ++i) acc[i] = make_float2(0.f, 0.f);
    for (int k4 = 0; k4 < 128; k4 += 4) {
        float2 wr[4], wx[4];
        #pragma unroll
        for (int kk = 0; kk < 4; ++kk) {
            wr[kk] = *(const float2*)&Wr[(k4 + kk) * 128 + c0];
            wx[kk] = *(const float2*)&Wx[(k4 + kk) * 128 + c0];
        }
        #pragma unroll
        for (int i = 0; i < 8; ++i) {
            int r = h * 8 + i;
            float4 a4 = *(const float4*)&aL[r * 128 + k4];
            float4 x4 = *(const float4*)&xL[r * 128 + k4];
            acc[i].x += a4.x * wr[0].x + a4.y * wr[1].x + a4.z * wr[2].x + a4.w * wr[3].x
                      + x4.x * wx[0].x + x4.y * wx[1].x + x4.z * wx[2].x + x4.w * wx[3].x;
            acc[i].y += a4.x * wr[0].y + a4.y * wr[1].y + a4.z * wr[2].y + a4.w * wr[3].y
                      + x4.x * wx[0].y + x4.y * wx[1].y + x4.z * wx[2].y + x4.w * wx[3].y;
        }
    }
    float b0 = bias[c0], b1v = bias[c0 + 1];
    __syncthreads();
    #pragma unroll
    for (int i = 0; i < 8; ++i) {
        int r = h * 8 + i;
        aL[r * 128 + c0]     = acc[i].x + b0;
        aL[r * 128 + c0 + 1] = acc[i].y + b1v;
    }
    __syncthreads();
    int lane = tid & 63;
    #pragma unroll
    for (int i = 0; i < 8; ++i) {
        int r = h * 8 + i;
        float v0 = aL[r * 128 + lane], v1 = aL[r * 128 + lane + 64];
        float s = v0 * v0 + v1 * v1;
        #pragma unroll
        for (int off = 32; off >= 1; off >>= 1) s += __shfl_xor(s, off);
        float nrm = fmaxf(sqrtf(s), 1e-12f);
        float mf = (mask[row0 + r] != 0) ? 1.f : 0.f;
        float inv = mf / nrm;
        float p0 = fmaxf(v0 * inv, 0.f), p1 = fmaxf(v1 * inv, 0.f);
        P[(row0 + r) * 128 + lane]      = p0;
        P[(row0 + r) * 128 + lane + 64] = p1;
        aL[r * 128 + lane] = p0; aL[r * 128 + lane + 64] = p1;
    }
    __syncthreads();
    if (tid < 128) {
        float s = 0.f, q = 0.f;
        #pragma unroll
        for (int r = 0; r < 32; ++r) { float v = aL[r * 128 + tid]; s += v; q += v * v; }
        atomicAdd(&bnstat[tid], s);
        atomicAdd(&bnstat[128 + tid], q);
    }
}

// ---------------- K10: BatchNorm apply (training stats, biased var), in place ----------------
__global__ __launch_bounds__(256) void k10_bn(float* __restrict__ P,
        const float* __restrict__ bn, const float* __restrict__ g,
        const float* __restrict__ be) {
    int c = threadIdx.x & 127;
    int half = threadIdx.x >> 7;
    size_t base = (size_t)blockIdx.x * 16;
    float mean = bn[c] * (1.f / 16384.f);
    float var  = bn[128 + c] * (1.f / 16384.f) - mean * mean;
    float sc = g[c] * rsqrtf(var + 1e-5f);
    float sh = be[c] - mean * sc;
    for (int r = half; r < 16; r += 2) {
        size_t i = (base + r) * 128 + c;
        P[i] = P[i] * sc + sh;
    }
}

// ---------------- K11: final (concat * mf) @ Wl + bl, * mf ----------------
__global__ __launch_bounds__(256) void k11_final(const float* __restrict__ h1,
        const float* __restrict__ h2, const float* __restrict__ h3,
        const float* __restrict__ Wl, const float* __restrict__ bl,
        const int* __restrict__ mask, float* __restrict__ out) {
    __shared__ float s1[32 * 128], s2[32 * 128], s3[32 * 128];
    int tid = threadIdx.x;
    size_t row0 = (size_t)blockIdx.x * 32;
    for (int t = tid * 4; t < 32 * 128; t += 1024) {
        int r = t >> 7;
        float mf = (mask[row0 + r] != 0) ? 1.f : 0.f;
        float4 a = *(const float4*)&h1[row0 * 128 + t];
        float4 b = *(const float4*)&h2[row0 * 128 + t];
        float4 c = *(const float4*)&h3[row0 * 128 + t];
        a.x *= mf; a.y *= mf; a.z *= mf; a.w *= mf;
        b.x *= mf; b.y *= mf; b.z *= mf; b.w *= mf;
        c.x *= mf; c.y *= mf; c.z *= mf; c.w *= mf;
        *(float4*)&s1[t] = a; *(float4*)&s2[t] = b; *(float4*)&s3[t] = c;
    }
    __syncthreads();
    int h = tid >> 6, c0 = (tid & 63) * 2;
    float2 acc[8];
    #pragma unroll
    for (int i = 0; i < 8; ++i) acc[i] = make_float2(0.f, 0.f);
    for (int k4 = 0; k4 < 128; k4 += 4) {
        float2 w1[4], w2[4], w3[4];
        #pragma unroll
        for (int kk = 0; kk < 4; ++kk) {
            w1[kk] = *(const float2*)&Wl[(k4 + kk) * 128 + c0];
            w2[kk] = *(const float2*)&Wl[(128 + k4 + kk) * 128 + c0];
            w3[kk] = *(const float2*)&Wl[(256 + k4 + kk) * 128 + c0];
        }
        #pragma unroll
        for (int i = 0; i < 8; ++i) {
            int r = h * 8 + i;
            float4 a = *(const float4*)&s1[r * 128 + k4];
            float4 b = *(const float4*)&s2[r * 128 + k4];
            float4 c = *(const float4*)&s3[r * 128 + k4];
            acc[i].x += a.x * w1[0].x + a.y * w1[1].x + a.z * w1[2].x + a.w * w1[3].x
                      + b.x * w2[0].x + b.y * w2[1].x + b.z * w2[2].x + b.w * w2[3].x
                      + c.x * w3[0].x + c.y * w3[1].x + c.z * w3[2].x + c.w * w3[3].x;
            acc[i].y += a.x * w1[0].y + a.y * w1[1].y + a.z * w1[2].y + a.w * w1[3].y
                      + b.x * w2[0].y + b.y * w2[1].y + b.z * w2[2].y + b.w * w2[3].y
                      + c.x * w3[0].y + c.y * w3[1].y + c.z * w3[2].y + c.w * w3[3].y;
        }
    }
    float bx = bl[c0], by = bl[c0 + 1];
    #pragma unroll
    for (int i = 0; i < 8; ++i) {
        int r = h * 8 + i;
        float mf = (mask[row0 + r] != 0) ? 1.f : 0.f;
        *(float2*)&out[(row0 + r) * 128 + c0] =
            make_float2((acc[i].x + bx) * mf, (acc[i].y + by) * mf);
    }
}

// ---------------- launch ----------------
extern "C" void kernel_launch(void* const* d_in, const int* in_sizes, int n_in,
                              void* d_out, int out_size, void* d_ws, size_t ws_size,
                              hipStream_t stream) {
    (void)in_sizes; (void)n_in; (void)out_size; (void)ws_size;
    const float* x    = (const float*)d_in[0];
    const float* adj  = (const float*)d_in[1];
    const int*   mask = (const int*)d_in[2];
    const float* Wr1 = (const float*)d_in[3],  *Wx1 = (const float*)d_in[4];
    const float* b1  = (const float*)d_in[5],  *g1  = (const float*)d_in[6],  *be1 = (const float*)d_in[7];
    const float* Wr2 = (const float*)d_in[8],  *Wx2 = (const float*)d_in[9];
    const float* b2  = (const float*)d_in[10], *g2  = (const float*)d_in[11], *be2 = (const float*)d_in[12];
    const float* Wr3 = (const float*)d_in[13], *Wx3 = (const float*)d_in[14];
    const float* b3  = (const float*)d_in[15], *g3  = (const float*)d_in[16], *be3 = (const float*)d_in[17];
    const float* Wl  = (const float*)d_in[18], *bl  = (const float*)d_in[19];

    char* ws = (char*)d_ws;
    uint32_t* bitset = (uint32_t*)(ws + OFF_BITSET);
    float*    agg    = (float*)(ws + OFF_AGG);
    float*    h1     = (float*)(ws + OFF_H1);
    float*    h2     = (float*)(ws + OFF_H2);
    float*    h3     = (float*)(ws + OFF_H3);
    uint16_t* cols   = (uint16_t*)(ws + OFF_COLS);
    uint32_t* packed = (uint32_t*)(ws + OFF_PACKED);
    uint32_t* rp     = (uint32_t*)(ws + OFF_RP);
    uint32_t* deg0   = (uint32_t*)(ws + OFF_DEG0);
    uint32_t* degf   = (uint32_t*)(ws + OFF_DEGF);
    uint32_t* rmaskg = (uint32_t*)(ws + OFF_RMASK);
    float*    bn     = (float*)(ws + OFF_BN);
    float*    out    = (float*)d_out;

    k0_zero   <<<1,    256, 0, stream>>>(bn);
    k1_bitset <<<4096, 256, 0, stream>>>(adj, bitset, deg0);
    k2_rowptr <<<8,    256, 0, stream>>>(deg0, rp);
    k3_cols   <<<4096, 256, 0, stream>>>(bitset, rp, cols);
    k4_packed <<<4096, 256, 0, stream>>>(cols, rp, packed);
    k5_dilate <<<8,    128, 0, stream>>>(packed, rp, deg0, mask, rmaskg, degf);
    k6_compact<<<4096, 256, 0, stream>>>(cols, rp, rmaskg);
    // layer 1
    k7_spmm   <<<4096, 256, 0, stream>>>(x,  cols, rp, degf, agg);
    k8_gemm   <<<512,  256, 0, stream>>>(agg, x,  Wr1, Wx1, b1, mask, h1, bn + 0);
    k10_bn    <<<1024, 256, 0, stream>>>(h1, bn + 0,   g1, be1);
    // layer 2
    k7_spmm   <<<4096, 256, 0, stream>>>(h1, cols, rp, degf, agg);
    k8_gemm   <<<512,  256, 0, stream>>>(agg, h1, Wr2, Wx2, b2, mask, h2, bn + 256);
    k10_bn    <<<1024, 256, 0, stream>>>(h2, bn + 256, g2, be2);
    // layer 3
    k7_spmm   <<<4096, 256, 0, stream>>>(h2, cols, rp, degf, agg);
    k8_gemm   <<<512,  256, 0, stream>>>(agg, h2, Wr3, Wx3, b3, mask, h3, bn + 512);
    k10_bn    <<<1024, 256, 0, stream>>>(h3, bn + 512, g3, be3);
    // final
    k11_final <<<512,  256, 0, stream>>>(h1, h2, h3, Wl, bl, mask, out);
}

// Round 5
// 423.172 us; speedup vs baseline: 2.7846x; 2.2688x over previous
//
#include <hip/hip_runtime.h>
#include <cstdint>

// ---------------- problem constants ----------------
constexpr int B_ = 8, N_ = 2048, D_ = 128, NW = 64;   // NW = words per bitset row
constexpr int EMAX = 131072;                           // per-batch edge capacity
constexpr int RPS = 2064;                              // rowptr stride per batch
constexpr int TDIL = 10;

// ---------------- workspace layout (bytes) ----------------
constexpr size_t OFF_BITSET = 0;                  // 4MB (preproc), reused as agg (8MB)
constexpr size_t OFF_AGG    = 0;
constexpr size_t OFF_H1     = (size_t)8  << 20;
constexpr size_t OFF_H2     = (size_t)16 << 20;
constexpr size_t OFF_H3     = (size_t)24 << 20;
constexpr size_t OFF_COLS   = (size_t)32 << 20;   // u16 [B][EMAX]  (2MB)
constexpr size_t OFF_PACKED = (size_t)34 << 20;   // u32 [B][EMAX]  (4MB): col | mlocal<<16
constexpr size_t OFF_RP     = (size_t)38 << 20;   // u32 [B][RPS]
constexpr size_t OFF_DEG0   = OFF_RP   + ((size_t)128 << 10);
constexpr size_t OFF_DEGF   = OFF_DEG0 + ((size_t)64  << 10);
constexpr size_t OFF_RMASK  = OFF_DEGF + ((size_t)64  << 10);  // u32 [B][N][4] (256KB)
constexpr size_t OFF_BN     = OFF_RMASK + ((size_t)256 << 10); // 3*256 floats

// ---------------- K0: zero BN stats ----------------
__global__ void k0_zero(float* bn) {
    for (int i = threadIdx.x; i < 768; i += 256) bn[i] = 0.f;
}

// ---------------- K1: adj (fp32 0/1) -> bitset + degrees ----------------
__global__ __launch_bounds__(256) void k1_bitset(const float* __restrict__ adj,
        uint32_t* __restrict__ bitset, uint32_t* __restrict__ deg0) {
    int row  = blockIdx.x * 4 + (threadIdx.x >> 6);
    int lane = threadIdx.x & 63;
    const float* ar = adj + (size_t)row * N_;
    uint32_t myw = 0;
    #pragma unroll 4
    for (int it = 0; it < 32; ++it) {
        float v = ar[it * 64 + lane];
        unsigned long long m = __ballot(v != 0.0f);
        if (lane == 2 * it)          myw = (uint32_t)m;
        else if (lane == 2 * it + 1) myw = (uint32_t)(m >> 32);
    }
    bitset[(size_t)row * NW + lane] = myw;
    int pc = __popc(myw);
    #pragma unroll
    for (int off = 32; off >= 1; off >>= 1) pc += __shfl_xor(pc, off);
    if (lane == 0) deg0[row] = (uint32_t)pc;
}

// ---------------- K2: per-batch prefix sum of degrees -> rowptr ----------------
__global__ __launch_bounds__(256) void k2_rowptr(const uint32_t* __restrict__ deg0,
        uint32_t* __restrict__ rowptr) {
    int b = blockIdx.x, t = threadIdx.x;
    __shared__ uint32_t tsum[256];
    uint32_t v[8]; uint32_t s = 0;
    #pragma unroll
    for (int j = 0; j < 8; ++j) { v[j] = deg0[b * N_ + t * 8 + j]; s += v[j]; v[j] = s; }
    tsum[t] = s;
    __syncthreads();
    for (int off = 1; off < 256; off <<= 1) {
        uint32_t xv = (t >= off) ? tsum[t - off] : 0u;
        __syncthreads();
        tsum[t] += xv;
        __syncthreads();
    }
    uint32_t excl = tsum[t] - s;
    uint32_t* rp = rowptr + (size_t)b * RPS;
    if (t == 0) rp[0] = 0;
    #pragma unroll
    for (int j = 0; j < 8; ++j) {
        uint32_t val = excl + v[j];
        if (val > (uint32_t)EMAX) val = EMAX;   // safety clamp
        rp[t * 8 + j + 1] = val;
    }
}

// ---------------- K3: fill sorted column lists ----------------
__global__ __launch_bounds__(256) void k3_cols(const uint32_t* __restrict__ bitset,
        const uint32_t* __restrict__ rowptr, uint16_t* __restrict__ cols) {
    int row  = blockIdx.x * 4 + (threadIdx.x >> 6);
    int lane = threadIdx.x & 63;
    int b = row >> 11, n = row & (N_ - 1);
    uint32_t w = bitset[(size_t)row * NW + lane];
    uint32_t pc = __popc(w);
    uint32_t inc = pc;
    #pragma unroll
    for (int off = 1; off < 64; off <<= 1) {
        uint32_t t = __shfl_up(inc, off);
        if (lane >= off) inc += t;
    }
    uint32_t base = rowptr[(size_t)b * RPS + n] + (inc - pc);
    uint16_t* cb = cols + (size_t)b * EMAX;
    while (w) {
        int bit = __builtin_ctz(w); w &= w - 1;
        if (base < (uint32_t)EMAX) cb[base] = (uint16_t)(lane * 32 + bit);
        ++base;
    }
}

// ---------------- K4: packed (col | mate_local<<16) via binary search ----------------
__global__ __launch_bounds__(256) void k4_packed(const uint16_t* __restrict__ cols,
        const uint32_t* __restrict__ rowptr, uint32_t* __restrict__ packed) {
    int row  = blockIdx.x * 4 + (threadIdx.x >> 6);
    int lane = threadIdx.x & 63;
    int b = row >> 11, n = row & (N_ - 1);
    const uint32_t* rpb = rowptr + (size_t)b * RPS;
    const uint16_t* cb  = cols + (size_t)b * EMAX;
    uint32_t start = rpb[n], end = rpb[n + 1];
    for (uint32_t e = start + lane; e < end; e += 64) {
        uint32_t j = cb[e];
        uint32_t lo = rpb[j], hi = rpb[j + 1];
        uint32_t rj = lo;
        while (lo < hi) {
            uint32_t mid = (lo + hi) >> 1;
            if ((int)cb[mid] < n) lo = mid + 1; else hi = mid;
        }
        packed[(size_t)b * EMAX + e] = j | ((lo - rj) << 16);
    }
}

// ---------------- K5: DAG-parallel dilation (16 waves per batch) ----------------
// Row n depends ONLY on its earlier original neighbors m<n (they are the only
// writers of rm4[n] before step n; later neighbors m'>n must themselves wait
// for n, so they cannot touch rm4[n] early). Wave w owns rows n===w (mod 16),
// processed in increasing order -> deadlock-free (smallest unprocessed row
// always has all deps satisfied). Sync via per-row done-bits in LDS with
// acquire loads / release fetch_or.
__global__ __launch_bounds__(1024) void k5_dilate(
        const uint32_t* __restrict__ packed, const uint32_t* __restrict__ rowptr,
        const uint32_t* __restrict__ deg0, const int* __restrict__ mask,
        uint32_t* __restrict__ rmaskg, uint32_t* __restrict__ degf) {
    int b = blockIdx.x;
    int tid = threadIdx.x;
    int lane = tid & 63;
    int wv = tid >> 6;                                // 0..15
    __shared__ __align__(16) uint32_t rm4[N_ * 4];    // 32KB
    __shared__ uint32_t rps[N_ + 1];                  // 8.2KB
    __shared__ uint8_t  mk[N_];                       // 2KB
    __shared__ uint32_t done[64];                     // 2048 done-bits
    const uint32_t* pkg = packed + (size_t)b * EMAX;
    const uint32_t* rpg = rowptr + (size_t)b * RPS;

    for (int i = tid; i <= N_; i += 1024) rps[i] = rpg[i];
    if (tid < 64) done[tid] = 0u;
    for (int i = tid; i < N_; i += 1024) {
        int d = (int)deg0[b * N_ + i]; if (d > 128) d = 128;
        uint4 mm;
        mm.x = (d >= 32) ? ~0u : ((d > 0)  ? ((1u << d)        - 1u) : 0u);
        mm.y = (d >= 64) ? ~0u : ((d > 32) ? ((1u << (d - 32)) - 1u) : 0u);
        mm.z = (d >= 96) ? ~0u : ((d > 64) ? ((1u << (d - 64)) - 1u) : 0u);
        mm.w = (d >= 128)? ~0u : ((d > 96) ? ((1u << (d - 96)) - 1u) : 0u);
        *(uint4*)&rm4[(size_t)i * 4] = mm;
        mk[i] = (uint8_t)(mask[b * N_ + i] != 0);
    }
    __syncthreads();

    unsigned long long below = (1ULL << lane) - 1ULL;
    // first owned row's packed entries
    int n = wv;
    uint32_t ld = rps[n], en = rps[n + 1];
    int cnt = (int)(en - ld);
    uint32_t pk0 = (lane < cnt)      ? pkg[ld + lane]      : 0xFFFFFFFFu;
    uint32_t pk1 = (lane + 64 < cnt) ? pkg[ld + 64 + lane] : 0xFFFFFFFFu;

    while (n < N_) {
        // prefetch next owned row's packed entries (latency hidden under spin/process)
        int nn = n + 16;
        int cntN = 0;
        uint32_t pk0N = 0xFFFFFFFFu, pk1N = 0xFFFFFFFFu;
        if (nn < N_) {
            uint32_t ldN = rps[nn], enN = rps[nn + 1];
            cntN = (int)(enN - ldN);
            pk0N = (lane < cntN)      ? pkg[ldN + lane]      : 0xFFFFFFFFu;
            pk1N = (lane + 64 < cntN) ? pkg[ldN + 64 + lane] : 0xFFFFFFFFu;
        }

        uint32_t c0 = pk0 & 0xFFFFu, c1 = pk1 & 0xFFFFu;
        bool e0 = (lane < cnt)      && (c0 < (uint32_t)n);
        bool e1 = (lane + 64 < cnt) && (c1 < (uint32_t)n);
        // spin until all earlier original neighbors are done
        while (true) {
            uint32_t d0 = e0 ? __hip_atomic_load(&done[c0 >> 5], __ATOMIC_ACQUIRE,
                                                 __HIP_MEMORY_SCOPE_WORKGROUP) : 0u;
            uint32_t d1 = e1 ? __hip_atomic_load(&done[c1 >> 5], __ATOMIC_ACQUIRE,
                                                 __HIP_MEMORY_SCOPE_WORKGROUP) : 0u;
            bool ok0 = !e0 || ((d0 >> (c0 & 31)) & 1u);
            bool ok1 = !e1 || ((d1 >> (c1 & 31)) & 1u);
            if (__all((int)(ok0 && ok1))) break;
            __builtin_amdgcn_s_sleep(1);
        }

        // process row n (all its incoming removals have been applied)
        uint4 mcur = *(const uint4*)&rm4[(size_t)n * 4];
        uint32_t w01 = (lane < 32) ? mcur.x : mcur.y;
        uint32_t w23 = (lane < 32) ? mcur.z : mcur.w;
        uint32_t a0 = (w01 >> (lane & 31)) & 1u;
        uint32_t a1 = (w23 >> (lane & 31)) & 1u;
        unsigned long long bl0 = __ballot(a0 != 0), bl1 = __ballot(a1 != 0);
        uint32_t num = (uint32_t)__popcll(bl0) + (uint32_t)__popcll(bl1);
        if (mk[n] && num > 1u) {
            bool allrm = num <= (uint32_t)TDIL;         // sf==1 -> remove all
            uint32_t sf = (num + 1u) >> 1;              // ceil(num/2)
            uint32_t r2 = (num & 1u) ? 0xFFFFFFFFu : num;
            uint32_t rank0 = (uint32_t)__popcll(bl0 & below) + 1u;
            uint32_t rank1 = (uint32_t)__popcll(bl0) + (uint32_t)__popcll(bl1 & below) + 1u;
            bool rm0 = a0 && (allrm || rank0 == sf || rank0 == r2);
            bool rm1 = a1 && (allrm || rank1 == sf || rank1 == r2);
            unsigned long long rb0 = __ballot(rm0), rb1 = __ballot(rm1);
            if (rm0) {
                uint32_t c = pk0 & 0xFFFFu, ml = pk0 >> 16;
                if (ml < 128u) atomicAnd(&rm4[c * 4 + (ml >> 5)], ~(1u << (ml & 31)));
            }
            if (rm1) {
                uint32_t c = pk1 & 0xFFFFu, ml = pk1 >> 16;
                if (ml < 128u) atomicAnd(&rm4[c * 4 + (ml >> 5)], ~(1u << (ml & 31)));
            }
            if (lane == 0) {
                uint4 nm;
                nm.x = mcur.x & ~(uint32_t)rb0;
                nm.y = mcur.y & ~(uint32_t)(rb0 >> 32);
                nm.z = mcur.z & ~(uint32_t)rb1;
                nm.w = mcur.w & ~(uint32_t)(rb1 >> 32);
                *(uint4*)&rm4[(size_t)n * 4] = nm;
            }
        }
        // release: all this wave's ds ops (atomics + own-mask write) drain first
        if (lane == 0)
            __hip_atomic_fetch_or(&done[n >> 5], 1u << (n & 31),
                    __ATOMIC_RELEASE, __HIP_MEMORY_SCOPE_WORKGROUP);

        n = nn; cnt = cntN; pk0 = pk0N; pk1 = pk1N;
    }
    __syncthreads();
    for (int i = tid; i < N_; i += 1024) {
        uint4 mm = *(const uint4*)&rm4[(size_t)i * 4];
        *(uint4*)&rmaskg[((size_t)b * N_ + i) * 4] = mm;
        degf[b * N_ + i] = (uint32_t)(__popc(mm.x) + __popc(mm.y) + __popc(mm.z) + __popc(mm.w));
    }
}

// ---------------- K6: compact surviving cols in place (from rank masks) ----------------
__global__ __launch_bounds__(256) void k6_compact(uint16_t* __restrict__ cols,
        const uint32_t* __restrict__ rowptr, const uint32_t* __restrict__ rmaskg) {
    int row  = blockIdx.x * 4 + (threadIdx.x >> 6);
    int lane = threadIdx.x & 63;
    int b = row >> 11, n = row & (N_ - 1);
    uint16_t* cb = cols + (size_t)b * EMAX;
    uint4 mm = *(const uint4*)&rmaskg[(size_t)row * 4];
    uint32_t st = rowptr[(size_t)b * RPS + n];
    uint32_t w01 = (lane < 32) ? mm.x : mm.y;
    uint32_t w23 = (lane < 32) ? mm.z : mm.w;
    uint32_t a0 = (w01 >> (lane & 31)) & 1u;
    uint32_t a1 = (w23 >> (lane & 31)) & 1u;
    unsigned long long b0 = __ballot(a0 != 0), b1 = __ballot(a1 != 0);
    unsigned long long below = (1ULL << lane) - 1ULL;
    uint16_t c0v = 0, c1v = 0;
    if (a0) c0v = cb[st + lane];
    if (a1) c1v = cb[st + 64 + lane];
    uint32_t i0 = st + (uint32_t)__popcll(b0 & below);
    uint32_t i1 = st + (uint32_t)__popcll(b0) + (uint32_t)__popcll(b1 & below);
    if (a0) cb[i0] = c0v;
    if (a1) cb[i1] = c1v;
}

// ---------------- K7: SpMM mean-aggregate (1 wave per row) ----------------
__global__ __launch_bounds__(256) void k7_spmm(const float* __restrict__ X,
        const uint16_t* __restrict__ cols, const uint32_t* __restrict__ rowptr,
        const uint32_t* __restrict__ degf, float* __restrict__ agg) {
    int wid  = blockIdx.x * 4 + (threadIdx.x >> 6);
    int lane = threadIdx.x & 63;
    int b = wid >> 11, n = wid & (N_ - 1);
    const uint16_t* cb = cols + (size_t)b * EMAX;
    uint32_t start = rowptr[(size_t)b * RPS + n];
    uint32_t cnt = degf[wid];
    const float* Xb = X + ((size_t)b * N_) * D_;
    float ax = 0.f, ay = 0.f;
    for (uint32_t base = 0; base < cnt; base += 64) {
        int idx = (int)base + lane;
        int cl = (idx < (int)cnt) ? (int)cb[start + idx] : 0;
        int kmax = (int)cnt - (int)base; if (kmax > 64) kmax = 64;
        for (int k = 0; k < kmax; ++k) {
            int c = __shfl(cl, k);
            float2 v = ((const float2*)(Xb + (size_t)c * D_))[lane];
            ax += v.x; ay += v.y;
        }
    }
    float inv = 1.0f / (float)(cnt ? cnt : 1u);
    ((float2*)(agg + (size_t)wid * D_))[lane] = make_float2(ax * inv, ay * inv);
}

// ---------------- K8: sage GEMM + bias + L2norm + mask + relu + BN partials ----------------
__global__ __launch_bounds__(256) void k8_gemm(const float* __restrict__ agg,
        const float* __restrict__ X, const float* __restrict__ Wr,
        const float* __restrict__ Wx, const float* __restrict__ bias,
        const int* __restrict__ mask, float* __restrict__ P,
        float* __restrict__ bnstat) {
    __shared__ float aL[32 * 128];
    __shared__ float xL[32 * 128];
    int tid = threadIdx.x;
    size_t row0 = (size_t)blockIdx.x * 32;
    for (int t = tid * 4; t < 32 * 128; t += 1024) {
        *(float4*)&aL[t] = *(const float4*)&agg[row0 * 128 + t];
        *(float4*)&xL[t] = *(const float4*)&X[row0 * 128 + t];
    }
    __syncthreads();
    int h = tid >> 6;
    int c0 = (tid & 63) * 2;
    float2 acc[8];
    #pragma unroll
    for (int i = 0; i < 8; ++i) acc[i] = make_float2(0.f, 0.f);
    for (int k4 = 0; k4 < 128; k4 += 4) {
        float2 wr[4], wx[4];
        #pragma unroll
        for (int kk = 0; kk < 4; ++kk) {
            wr[kk] = *(const float2*)&Wr[(k4 + kk) * 128 + c0];
            wx[kk] = *(const float2*)&Wx[(k4 + kk) * 128 + c0];
        }
        #pragma unroll
        for (int i = 0; i < 8; ++i) {
            int r = h * 8 + i;
            float4 a4 = *(const float4*)&aL[r * 128 + k4];
            float4 x4 = *(const float4*)&xL[r * 128 + k4];
            acc[i].x += a4.x * wr[0].x + a4.y * wr[1].x + a4.z * wr[2].x + a4.w * wr[3].x
                      + x4.x * wx[0].x + x4.y * wx[1].x + x4.z * wx[2].x + x4.w * wx[3].x;
            acc[i].y += a4.x * wr[0].y + a4.y * wr[1].y + a4.z * wr[2].y + a4.w * wr[3].y
                      + x4.x * wx[0].y + x4.y * wx[1].y + x4.z * wx[2].y + x4.w * wx[3].y;
        }
    }
    float b0 = bias[c0], b1v = bias[c0 + 1];
    __syncthreads();
    #pragma unroll
    for (int i = 0; i < 8; ++i) {
        int r = h * 8 + i;
        aL[r * 128 + c0]     = acc[i].x + b0;
        aL[r * 128 + c0 + 1] = acc[i].y + b1v;
    }
    __syncthreads();
    int lane = tid & 63;
    #pragma unroll
    for (int i = 0; i < 8; ++i) {
        int r = h * 8 + i;
        float v0 = aL[r * 128 + lane], v1 = aL[r * 128 + lane + 64];
        float s = v0 * v0 + v1 * v1;
        #pragma unroll
        for (int off = 32; off >= 1; off >>= 1) s += __shfl_xor(s, off);
        float nrm = fmaxf(sqrtf(s), 1e-12f);
        float mf = (mask[row0 + r] != 0) ? 1.f : 0.f;
        float inv = mf / nrm;
        float p0 = fmaxf(v0 * inv, 0.f), p1 = fmaxf(v1 * inv, 0.f);
        P[(row0 + r) * 128 + lane]      = p0;
        P[(row0 + r) * 128 + lane + 64] = p1;
        aL[r * 128 + lane] = p0; aL[r * 128 + lane + 64] = p1;
    }
    __syncthreads();
    if (tid < 128) {
        float s = 0.f, q = 0.f;
        #pragma unroll
        for (int r = 0; r < 32; ++r) { float v = aL[r * 128 + tid]; s += v; q += v * v; }
        atomicAdd(&bnstat[tid], s);
        atomicAdd(&bnstat[128 + tid], q);
    }
}

// ---------------- K10: BatchNorm apply (training stats, biased var), in place ----------------
__global__ __launch_bounds__(256) void k10_bn(float* __restrict__ P,
        const float* __restrict__ bn, const float* __restrict__ g,
        const float* __restrict__ be) {
    int c = threadIdx.x & 127;
    int half = threadIdx.x >> 7;
    size_t base = (size_t)blockIdx.x * 16;
    float mean = bn[c] * (1.f / 16384.f);
    float var  = bn[128 + c] * (1.f / 16384.f) - mean * mean;
    float sc = g[c] * rsqrtf(var + 1e-5f);
    float sh = be[c] - mean * sc;
    for (int r = half; r < 16; r += 2) {
        size_t i = (base + r) * 128 + c;
        P[i] = P[i] * sc + sh;
    }
}

// ---------------- K11: final (concat * mf) @ Wl + bl, * mf ----------------
__global__ __launch_bounds__(256) void k11_final(const float* __restrict__ h1,
        const float* __restrict__ h2, const float* __restrict__ h3,
        const float* __restrict__ Wl, const float* __restrict__ bl,
        const int* __restrict__ mask, float* __restrict__ out) {
    __shared__ float s1[32 * 128], s2[32 * 128], s3[32 * 128];
    int tid = threadIdx.x;
    size_t row0 = (size_t)blockIdx.x * 32;
    for (int t = tid * 4; t < 32 * 128; t += 1024) {
        int r = t >> 7;
        float mf = (mask[row0 + r] != 0) ? 1.f : 0.f;
        float4 a = *(const float4*)&h1[row0 * 128 + t];
        float4 b = *(const float4*)&h2[row0 * 128 + t];
        float4 c = *(const float4*)&h3[row0 * 128 + t];
        a.x *= mf; a.y *= mf; a.z *= mf; a.w *= mf;
        b.x *= mf; b.y *= mf; b.z *= mf; b.w *= mf;
        c.x *= mf; c.y *= mf; c.z *= mf; c.w *= mf;
        *(float4*)&s1[t] = a; *(float4*)&s2[t] = b; *(float4*)&s3[t] = c;
    }
    __syncthreads();
    int h = tid >> 6, c0 = (tid & 63) * 2;
    float2 acc[8];
    #pragma unroll
    for (int i = 0; i < 8; ++i) acc[i] = make_float2(0.f, 0.f);
    for (int k4 = 0; k4 < 128; k4 += 4) {
        float2 w1[4], w2[4], w3[4];
        #pragma unroll
        for (int kk = 0; kk < 4; ++kk) {
            w1[kk] = *(const float2*)&Wl[(k4 + kk) * 128 + c0];
            w2[kk] = *(const float2*)&Wl[(128 + k4 + kk) * 128 + c0];
            w3[kk] = *(const float2*)&Wl[(256 + k4 + kk) * 128 + c0];
        }
        #pragma unroll
        for (int i = 0; i < 8; ++i) {
            int r = h * 8 + i;
            float4 a = *(const float4*)&s1[r * 128 + k4];
            float4 b = *(const float4*)&s2[r * 128 + k4];
            float4 c = *(const float4*)&s3[r * 128 + k4];
            acc[i].x += a.x * w1[0].x + a.y * w1[1].x + a.z * w1[2].x + a.w * w1[3].x
                      + b.x * w2[0].x + b.y * w2[1].x + b.z * w2[2].x + b.w * w2[3].x
                      + c.x * w3[0].x + c.y * w3[1].x + c.z * w3[2].x + c.w * w3[3].x;
            acc[i].y += a.x * w1[0].y + a.y * w1[1].y + a.z * w1[2].y + a.w * w1[3].y
                      + b.x * w2[0].y + b.y * w2[1].y + b.z * w2[2].y + b.w * w2[3].y
                      + c.x * w3[0].y + c.y * w3[1].y + c.z * w3[2].y + c.w * w3[3].y;
        }
    }
    float bx = bl[c0], by = bl[c0 + 1];
    #pragma unroll
    for (int i = 0; i < 8; ++i) {
        int r = h * 8 + i;
        float mf = (mask[row0 + r] != 0) ? 1.f : 0.f;
        *(float2*)&out[(row0 + r) * 128 + c0] =
            make_float2((acc[i].x + bx) * mf, (acc[i].y + by) * mf);
    }
}

// ---------------- launch ----------------
extern "C" void kernel_launch(void* const* d_in, const int* in_sizes, int n_in,
                              void* d_out, int out_size, void* d_ws, size_t ws_size,
                              hipStream_t stream) {
    (void)in_sizes; (void)n_in; (void)out_size; (void)ws_size;
    const float* x    = (const float*)d_in[0];
    const float* adj  = (const float*)d_in[1];
    const int*   mask = (const int*)d_in[2];
    const float* Wr1 = (const float*)d_in[3],  *Wx1 = (const float*)d_in[4];
    const float* b1  = (const float*)d_in[5],  *g1  = (const float*)d_in[6],  *be1 = (const float*)d_in[7];
    const float* Wr2 = (const float*)d_in[8],  *Wx2 = (const float*)d_in[9];
    const float* b2  = (const float*)d_in[10], *g2  = (const float*)d_in[11], *be2 = (const float*)d_in[12];
    const float* Wr3 = (const float*)d_in[13], *Wx3 = (const float*)d_in[14];
    const float* b3  = (const float*)d_in[15], *g3  = (const float*)d_in[16], *be3 = (const float*)d_in[17];
    const float* Wl  = (const float*)d_in[18], *bl  = (const float*)d_in[19];

    char* ws = (char*)d_ws;
    uint32_t* bitset = (uint32_t*)(ws + OFF_BITSET);
    float*    agg    = (float*)(ws + OFF_AGG);
    float*    h1     = (float*)(ws + OFF_H1);
    float*    h2     = (float*)(ws + OFF_H2);
    float*    h3     = (float*)(ws + OFF_H3);
    uint16_t* cols   = (uint16_t*)(ws + OFF_COLS);
    uint32_t* packed = (uint32_t*)(ws + OFF_PACKED);
    uint32_t* rp     = (uint32_t*)(ws + OFF_RP);
    uint32_t* deg0   = (uint32_t*)(ws + OFF_DEG0);
    uint32_t* degf   = (uint32_t*)(ws + OFF_DEGF);
    uint32_t* rmaskg = (uint32_t*)(ws + OFF_RMASK);
    float*    bn     = (float*)(ws + OFF_BN);
    float*    out    = (float*)d_out;

    k0_zero   <<<1,    256, 0, stream>>>(bn);
    k1_bitset <<<4096, 256, 0, stream>>>(adj, bitset, deg0);
    k2_rowptr <<<8,    256, 0, stream>>>(deg0, rp);
    k3_cols   <<<4096, 256, 0, stream>>>(bitset, rp, cols);
    k4_packed <<<4096, 256, 0, stream>>>(cols, rp, packed);
    k5_dilate <<<8,    1024, 0, stream>>>(packed, rp, deg0, mask, rmaskg, degf);
    k6_compact<<<4096, 256, 0, stream>>>(cols, rp, rmaskg);
    // layer 1
    k7_spmm   <<<4096, 256, 0, stream>>>(x,  cols, rp, degf, agg);
    k8_gemm   <<<512,  256, 0, stream>>>(agg, x,  Wr1, Wx1, b1, mask, h1, bn + 0);
    k10_bn    <<<1024, 256, 0, stream>>>(h1, bn + 0,   g1, be1);
    // layer 2
    k7_spmm   <<<4096, 256, 0, stream>>>(h1, cols, rp, degf, agg);
    k8_gemm   <<<512,  256, 0, stream>>>(agg, h1, Wr2, Wx2, b2, mask, h2, bn + 256);
    k10_bn    <<<1024, 256, 0, stream>>>(h2, bn + 256, g2, be2);
    // layer 3
    k7_spmm   <<<4096, 256, 0, stream>>>(h2, cols, rp, degf, agg);
    k8_gemm   <<<512,  256, 0, stream>>>(agg, h2, Wr3, Wx3, b3, mask, h3, bn + 512);
    k10_bn    <<<1024, 256, 0, stream>>>(h3, bn + 512, g3, be3);
    // final
    k11_final <<<512,  256, 0, stream>>>(h1, h2, h3, Wl, bl, mask, out);
}